// Round 3
// baseline (4841.082 us; speedup 1.0000x reference)
//
#include <hip/hip_runtime.h>
#include <hip/hip_bf16.h>

constexpr int NF = 128;
constexpr float BN_EPS_C = 1e-5f;

__device__ __forceinline__ void atomAddF(float* p, float v) {
  unsafeAtomicAdd(p, v);         // HW global_atomic_add_f32
}

// ---------------------------------------------------------------------------
// t[i] = h[i]  (float4 grid-stride-free copy)
// ---------------------------------------------------------------------------
__global__ __launch_bounds__(256)
void copy_f4(const float* __restrict__ in, float* __restrict__ out, long long n4)
{
  long long i = (long long)blockIdx.x * 256 + threadIdx.x;
  if (i < n4) ((float4*)out)[i] = ((const float4*)in)[i];
}

// ---------------------------------------------------------------------------
// Edge-parallel scatter-add: t[dst] += h[src].  32 lanes per edge, float4 each.
// ---------------------------------------------------------------------------
__global__ __launch_bounds__(256)
void scatter_add(const float* __restrict__ h, float* __restrict__ t,
                 const int* __restrict__ src, const int* __restrict__ dst, int E)
{
  long long idx = (long long)blockIdx.x * 256 + threadIdx.x;
  int e = (int)(idx >> 5);
  if (e >= E) return;
  int lane = (int)(idx & 31);
  int s = src[e], d = dst[e];
  float4 v = *(const float4*)(h + (long long)s * NF + lane * 4);
  float* p = t + (long long)d * NF + lane * 4;
  atomAddF(p + 0, v.x);
  atomAddF(p + 1, v.y);
  atomAddF(p + 2, v.z);
  atomAddF(p + 3, v.w);
}

// ---------------------------------------------------------------------------
// Naive, obviously-correct GEMM: block = one row (128 threads), thread j
// computes out[row][j] = relu(sum_k in[row][k] * W[k][j] + bias[j]).
// ---------------------------------------------------------------------------
__global__ __launch_bounds__(128)
void gemm_naive(const float* __restrict__ in, const float* __restrict__ W,
                const float* __restrict__ bias, float* __restrict__ out, int nrows)
{
  __shared__ float row[NF];
  int r = blockIdx.x;
  int j = threadIdx.x;
  row[j] = in[(long long)r * NF + j];
  __syncthreads();
  float acc = bias[j];
  for (int k = 0; k < NF; ++k)
    acc = fmaf(row[k], W[k * NF + j], acc);
  out[(long long)r * NF + j] = fmaxf(acc, 0.f);
}

// ---------------------------------------------------------------------------
// BN stats, stage 1: 128 blocks x 256 threads, deterministic fp64 partials.
// Block b covers rows r with (r mod 256) in {2b, 2b+1}. Thread: c=tid&127.
// part[b*128+c] = sum, part[16384 + b*128+c] = sumsq.
// ---------------------------------------------------------------------------
__global__ __launch_bounds__(256)
void bn_stats_partial(const float* __restrict__ v, double* __restrict__ part, int nrows)
{
  __shared__ double sd[2][NF], sq[2][NF];
  int tid = threadIdx.x;
  int c = tid & 127, ty = tid >> 7;
  int b = blockIdx.x;
  double s = 0.0, s2 = 0.0;
  for (long long r = b * 2 + ty; r < nrows; r += 256) {
    double x = (double)v[r * NF + c];
    s  += x;
    s2 += x * x;
  }
  sd[ty][c] = s;
  sq[ty][c] = s2;
  __syncthreads();
  if (ty == 0) {
    part[b * NF + c]             = sd[0][c] + sd[1][c];
    part[128 * NF + b * NF + c]  = sq[0][c] + sq[1][c];
  }
}

// ---------------------------------------------------------------------------
// BN stats, stage 2 + finalize: 1 block, 128 threads.
// scale = gamma * rsqrt(var+eps);  shift = beta - mu*scale
// ---------------------------------------------------------------------------
__global__ void bn_stats_final(const double* __restrict__ part,
                               const float* __restrict__ gamma,
                               const float* __restrict__ beta,
                               float* __restrict__ ss, int nrows)
{
  int c = threadIdx.x;
  double s = 0.0, s2 = 0.0;
  for (int b = 0; b < 128; ++b) {
    s  += part[b * NF + c];
    s2 += part[128 * NF + b * NF + c];
  }
  double invN = 1.0 / (double)nrows;
  double mu  = s * invN;
  double var = s2 * invN - mu * mu;
  double sc  = (double)gamma[c] / sqrt(var + (double)BN_EPS_C);
  ss[c]      = (float)sc;
  ss[NF + c] = (float)((double)beta[c] - mu * sc);
}

// ---------------------------------------------------------------------------
// BatchNorm apply: out = v*scale[c] + shift[c]
// ---------------------------------------------------------------------------
__global__ __launch_bounds__(256)
void bn_apply(const float* __restrict__ v, const float* __restrict__ ss,
              float* __restrict__ out, int nrows)
{
  long long i = (long long)blockIdx.x * 256 + threadIdx.x;  // float4 index
  long long total = (long long)nrows * (NF / 4);
  if (i >= total) return;
  int c = (int)(i & 31) * 4;
  float4 val = ((const float4*)v)[i];
  float4 o;
  o.x = fmaf(val.x, ss[c + 0], ss[NF + c + 0]);
  o.y = fmaf(val.y, ss[c + 1], ss[NF + c + 1]);
  o.z = fmaf(val.z, ss[c + 2], ss[NF + c + 2]);
  o.w = fmaf(val.w, ss[c + 3], ss[NF + c + 3]);
  ((float4*)out)[i] = o;
}

__global__ void copy_batch(const int* __restrict__ b, float* __restrict__ o, int n)
{
  int i = blockIdx.x * 256 + threadIdx.x;
  if (i < n) o[i] = (float)b[i];
}

// ---------------------------------------------------------------------------
extern "C" void kernel_launch(void* const* d_in, const int* in_sizes, int n_in,
                              void* d_out, int out_size, void* d_ws, size_t ws_size,
                              hipStream_t stream)
{
  const float* x     = (const float*)d_in[0];
  const int*   ei    = (const int*)  d_in[1];
  const int*   batch = (const int*)  d_in[2];
  const float* W1    = (const float*)d_in[3];
  const float* b1    = (const float*)d_in[4];
  const float* W2    = (const float*)d_in[5];
  const float* b2    = (const float*)d_in[6];
  const float* gamma = (const float*)d_in[7];
  const float* beta  = (const float*)d_in[8];

  const int N = in_sizes[2];
  const int E = in_sizes[1] / 2;
  const int L = in_sizes[4] / NF;

  const int* src = ei;
  const int* dst = ei + E;

  float*  t    = (float*)d_ws;                     // N*NF floats
  double* part = (double*)(t + (size_t)N * NF);    // 2*128*128 doubles
  float*  ss   = (float*)(part + 2 * 128 * NF);    // 256 floats (scale, shift)
  float*  hbuf = (float*)d_out;                    // N*NF, ping-pong + final h
  float*  outBatch = hbuf + (size_t)N * NF;

  const long long n4 = (long long)N * (NF / 4);
  const int cpBlocks = (int)((n4 + 255) / 256);
  const long long scatThreads = (long long)E * 32;
  const int scatBlocks = (int)((scatThreads + 255) / 256);

  const float* h = x;
  for (int l = 0; l < L; ++l) {
    // t = h + segment_sum(h[src], dst)
    copy_f4<<<cpBlocks, 256, 0, stream>>>(h, t, n4);
    scatter_add<<<scatBlocks, 256, 0, stream>>>(h, t, src, dst, E);
    // u = relu(t @ W1 + b1)  -> hbuf
    gemm_naive<<<N, 128, 0, stream>>>(t, W1 + (size_t)l * NF * NF,
                                      b1 + (size_t)l * NF, hbuf, N);
    // v = relu(u @ W2 + b2)  -> t
    gemm_naive<<<N, 128, 0, stream>>>(hbuf, W2 + (size_t)l * NF * NF,
                                      b2 + (size_t)l * NF, t, N);
    // BN stats (deterministic fp64 two-stage) + apply -> hbuf
    bn_stats_partial<<<128, 256, 0, stream>>>(t, part, N);
    bn_stats_final<<<1, NF, 0, stream>>>(part, gamma + (size_t)l * NF,
                                         beta + (size_t)l * NF, ss, N);
    bn_apply<<<cpBlocks, 256, 0, stream>>>(t, ss, hbuf, N);
    h = hbuf;
  }

  copy_batch<<<(N + 255) / 256, 256, 0, stream>>>(batch, outBatch, N);
}

// Round 4
// 1049.851 us; speedup vs baseline: 4.6112x; 4.6112x over previous
//
#include <hip/hip_runtime.h>
#include <hip/hip_bf16.h>

constexpr int NF = 128;
constexpr float BN_EPS_C = 1e-5f;

// ---------------------------------------------------------------------------
// CSR build: histogram -> 2-level exclusive scan -> fill (counting sort by dst)
// ---------------------------------------------------------------------------
__global__ __launch_bounds__(256)
void zero_counts(int* __restrict__ count, int n)
{
  int i = blockIdx.x * 256 + threadIdx.x;
  if (i < n) count[i] = 0;
}

__global__ __launch_bounds__(256)
void hist_dst(const int* __restrict__ dst, int* __restrict__ count, int E)
{
  int e = blockIdx.x * 256 + threadIdx.x;
  if (e < E) atomicAdd(&count[dst[e]], 1);
}

// chunk-local exclusive scan (256 elems/block) + chunk totals
__global__ __launch_bounds__(256)
void scan1(const int* __restrict__ count, int* __restrict__ excl,
           int* __restrict__ bsum, int n)
{
  __shared__ int s[256];
  int tid = threadIdx.x;
  int i = blockIdx.x * 256 + tid;
  int v = (i < n) ? count[i] : 0;
  s[tid] = v;
  __syncthreads();
  #pragma unroll
  for (int d = 1; d < 256; d <<= 1) {
    int t = (tid >= d) ? s[tid - d] : 0;
    __syncthreads();
    s[tid] += t;
    __syncthreads();
  }
  if (i < n) excl[i] = s[tid] - v;          // exclusive within chunk
  if (tid == 255) bsum[blockIdx.x] = s[255];
}

// exclusive scan of chunk totals (nb <= 256), in place
__global__ __launch_bounds__(256)
void scan2(int* __restrict__ bsum, int nb)
{
  __shared__ int s[256];
  int tid = threadIdx.x;
  int v = (tid < nb) ? bsum[tid] : 0;
  s[tid] = v;
  __syncthreads();
  #pragma unroll
  for (int d = 1; d < 256; d <<= 1) {
    int t = (tid >= d) ? s[tid - d] : 0;
    __syncthreads();
    s[tid] += t;
    __syncthreads();
  }
  if (tid < nb) bsum[tid] = s[tid] - v;
}

// add chunk offsets; init cursor; write row_off[n] = E
__global__ __launch_bounds__(256)
void scan3(int* __restrict__ row_off, const int* __restrict__ bsum,
           int* __restrict__ cursor, int n, int E)
{
  int i = blockIdx.x * 256 + threadIdx.x;
  if (i < n) {
    int o = row_off[i] + bsum[blockIdx.x];
    row_off[i] = o;
    cursor[i] = o;
  }
  if (i == 0) row_off[n] = E;
}

__global__ __launch_bounds__(256)
void fill_csr(const int* __restrict__ src, const int* __restrict__ dst,
              int* __restrict__ cursor, int* __restrict__ adj, int E)
{
  int e = blockIdx.x * 256 + threadIdx.x;
  if (e < E) {
    int pos = atomicAdd(&cursor[dst[e]], 1);
    adj[pos] = src[e];
  }
}

// ---------------------------------------------------------------------------
// Gather: t[i] = h[i] + sum_{j in adj[row_off[i]..row_off[i+1])} h[j]
// 32 lanes per node, float4 column slice per lane. adj loaded 32-wide and
// broadcast via shfl to keep the address chain off the critical path.
// ---------------------------------------------------------------------------
__global__ __launch_bounds__(256)
void gather_add(const float* __restrict__ h, const int* __restrict__ row_off,
                const int* __restrict__ adj, float* __restrict__ t, int n)
{
  int g = threadIdx.x >> 5, lane = threadIdx.x & 31;
  int node = blockIdx.x * 8 + g;
  if (node >= n) return;
  int beg = row_off[node], end = row_off[node + 1];

  float4 acc = *(const float4*)(h + (long long)node * NF + lane * 4);
  for (int base = beg; base < end; base += 32) {
    int cnt = min(32, end - base);
    int myadj = (lane < cnt) ? adj[base + lane] : 0;
    for (int k = 0; k < cnt; ++k) {
      int s = __shfl(myadj, k, 32);
      float4 v = *(const float4*)(h + (long long)s * NF + lane * 4);
      acc.x += v.x; acc.y += v.y; acc.z += v.z; acc.w += v.w;
    }
  }
  *(float4*)(t + (long long)node * NF + lane * 4) = acc;
}

// ---------------------------------------------------------------------------
// Naive GEMM (verified): block = one row, thread j computes one output col.
// ---------------------------------------------------------------------------
__global__ __launch_bounds__(128)
void gemm_naive(const float* __restrict__ in, const float* __restrict__ W,
                const float* __restrict__ bias, float* __restrict__ out, int nrows)
{
  __shared__ float row[NF];
  int r = blockIdx.x;
  int j = threadIdx.x;
  row[j] = in[(long long)r * NF + j];
  __syncthreads();
  float acc = bias[j];
  for (int k = 0; k < NF; ++k)
    acc = fmaf(row[k], W[k * NF + j], acc);
  out[(long long)r * NF + j] = fmaxf(acc, 0.f);
}

// ---------------------------------------------------------------------------
// BN stats stage 1: deterministic fp64 partials (128 blocks x 256 thr)
// ---------------------------------------------------------------------------
__global__ __launch_bounds__(256)
void bn_stats_partial(const float* __restrict__ v, double* __restrict__ part, int nrows)
{
  __shared__ double sd[2][NF], sq[2][NF];
  int tid = threadIdx.x;
  int c = tid & 127, ty = tid >> 7;
  int b = blockIdx.x;
  double s = 0.0, s2 = 0.0;
  for (long long r = b * 2 + ty; r < nrows; r += 256) {
    double x = (double)v[r * NF + c];
    s  += x;
    s2 += x * x;
  }
  sd[ty][c] = s;
  sq[ty][c] = s2;
  __syncthreads();
  if (ty == 0) {
    part[b * NF + c]            = sd[0][c] + sd[1][c];
    part[128 * NF + b * NF + c] = sq[0][c] + sq[1][c];
  }
}

__global__ void bn_stats_final(const double* __restrict__ part,
                               const float* __restrict__ gamma,
                               const float* __restrict__ beta,
                               float* __restrict__ ss, int nrows)
{
  int c = threadIdx.x;
  double s = 0.0, s2 = 0.0;
  for (int b = 0; b < 128; ++b) {
    s  += part[b * NF + c];
    s2 += part[128 * NF + b * NF + c];
  }
  double invN = 1.0 / (double)nrows;
  double mu  = s * invN;
  double var = s2 * invN - mu * mu;
  double sc  = (double)gamma[c] / sqrt(var + (double)BN_EPS_C);
  ss[c]      = (float)sc;
  ss[NF + c] = (float)((double)beta[c] - mu * sc);
}

__global__ __launch_bounds__(256)
void bn_apply(const float* __restrict__ v, const float* __restrict__ ss,
              float* __restrict__ out, int nrows)
{
  long long i = (long long)blockIdx.x * 256 + threadIdx.x;  // float4 index
  long long total = (long long)nrows * (NF / 4);
  if (i >= total) return;
  int c = (int)(i & 31) * 4;
  float4 val = ((const float4*)v)[i];
  float4 o;
  o.x = fmaf(val.x, ss[c + 0], ss[NF + c + 0]);
  o.y = fmaf(val.y, ss[c + 1], ss[NF + c + 1]);
  o.z = fmaf(val.z, ss[c + 2], ss[NF + c + 2]);
  o.w = fmaf(val.w, ss[c + 3], ss[NF + c + 3]);
  ((float4*)out)[i] = o;
}

__global__ void copy_batch(const int* __restrict__ b, float* __restrict__ o, int n)
{
  int i = blockIdx.x * 256 + threadIdx.x;
  if (i < n) o[i] = (float)b[i];
}

// ---------------------------------------------------------------------------
extern "C" void kernel_launch(void* const* d_in, const int* in_sizes, int n_in,
                              void* d_out, int out_size, void* d_ws, size_t ws_size,
                              hipStream_t stream)
{
  const float* x     = (const float*)d_in[0];
  const int*   ei    = (const int*)  d_in[1];
  const int*   batch = (const int*)  d_in[2];
  const float* W1    = (const float*)d_in[3];
  const float* b1    = (const float*)d_in[4];
  const float* W2    = (const float*)d_in[5];
  const float* b2    = (const float*)d_in[6];
  const float* gamma = (const float*)d_in[7];
  const float* beta  = (const float*)d_in[8];

  const int N = in_sizes[2];
  const int E = in_sizes[1] / 2;
  const int L = in_sizes[4] / NF;

  const int* src = ei;
  const int* dst = ei + E;

  // workspace layout
  float*  t       = (float*)d_ws;                      // N*NF
  double* part    = (double*)(t + (size_t)N * NF);     // 2*128*128
  float*  ss      = (float*)(part + 2 * 128 * NF);     // 256
  int*    count   = (int*)(ss + 256);                  // N
  int*    row_off = count + N;                         // N+1
  int*    cursor  = row_off + (N + 1);                 // N
  int*    adj     = cursor + N;                        // E
  int*    bsum    = adj + E;                           // 256

  float* hbuf = (float*)d_out;                         // N*NF ping-pong + final
  float* outBatch = hbuf + (size_t)N * NF;

  const long long n4 = (long long)N * (NF / 4);
  const int cpBlocks   = (int)((n4 + 255) / 256);
  const int eBlocks    = (E + 255) / 256;
  const int nBlocks256 = (N + 255) / 256;
  const int gthBlocks  = (N + 7) / 8;

  // ---- CSR build (once, reused by all layers) ----
  zero_counts<<<nBlocks256, 256, 0, stream>>>(count, N);
  hist_dst<<<eBlocks, 256, 0, stream>>>(dst, count, E);
  scan1<<<nBlocks256, 256, 0, stream>>>(count, row_off, bsum, N);
  scan2<<<1, 256, 0, stream>>>(bsum, nBlocks256);
  scan3<<<nBlocks256, 256, 0, stream>>>(row_off, bsum, cursor, N, E);
  fill_csr<<<eBlocks, 256, 0, stream>>>(src, dst, cursor, adj, E);

  // ---- layers ----
  const float* h = x;
  for (int l = 0; l < L; ++l) {
    gather_add<<<gthBlocks, 256, 0, stream>>>(h, row_off, adj, t, N);
    gemm_naive<<<N, 128, 0, stream>>>(t, W1 + (size_t)l * NF * NF,
                                      b1 + (size_t)l * NF, hbuf, N);
    gemm_naive<<<N, 128, 0, stream>>>(hbuf, W2 + (size_t)l * NF * NF,
                                      b2 + (size_t)l * NF, t, N);
    bn_stats_partial<<<128, 256, 0, stream>>>(t, part, N);
    bn_stats_final<<<1, NF, 0, stream>>>(part, gamma + (size_t)l * NF,
                                         beta + (size_t)l * NF, ss, N);
    bn_apply<<<cpBlocks, 256, 0, stream>>>(t, ss, hbuf, N);
    h = hbuf;
  }

  copy_batch<<<nBlocks256, 256, 0, stream>>>(batch, outBatch, N);
}

// Round 5
// 690.047 us; speedup vs baseline: 7.0156x; 1.5214x over previous
//
#include <hip/hip_runtime.h>
#include <hip/hip_bf16.h>

constexpr int NF = 128;
constexpr int BM = 64;               // rows per GEMM block
constexpr float BN_EPS_C = 1e-5f;

// ---------------------------------------------------------------------------
// CSR build: histogram -> 2-level exclusive scan -> fill (counting sort by dst)
// ---------------------------------------------------------------------------
__global__ __launch_bounds__(256)
void zero_counts(int* __restrict__ count, int n)
{
  int i = blockIdx.x * 256 + threadIdx.x;
  if (i < n) count[i] = 0;
}

__global__ __launch_bounds__(256)
void hist_dst(const int* __restrict__ dst, int* __restrict__ count, int E)
{
  int e = blockIdx.x * 256 + threadIdx.x;
  if (e < E) atomicAdd(&count[dst[e]], 1);
}

__global__ __launch_bounds__(256)
void scan1(const int* __restrict__ count, int* __restrict__ excl,
           int* __restrict__ bsum, int n)
{
  __shared__ int s[256];
  int tid = threadIdx.x;
  int i = blockIdx.x * 256 + tid;
  int v = (i < n) ? count[i] : 0;
  s[tid] = v;
  __syncthreads();
  #pragma unroll
  for (int d = 1; d < 256; d <<= 1) {
    int t = (tid >= d) ? s[tid - d] : 0;
    __syncthreads();
    s[tid] += t;
    __syncthreads();
  }
  if (i < n) excl[i] = s[tid] - v;
  if (tid == 255) bsum[blockIdx.x] = s[255];
}

__global__ __launch_bounds__(256)
void scan2(int* __restrict__ bsum, int nb)
{
  __shared__ int s[256];
  int tid = threadIdx.x;
  int v = (tid < nb) ? bsum[tid] : 0;
  s[tid] = v;
  __syncthreads();
  #pragma unroll
  for (int d = 1; d < 256; d <<= 1) {
    int t = (tid >= d) ? s[tid - d] : 0;
    __syncthreads();
    s[tid] += t;
    __syncthreads();
  }
  if (tid < nb) bsum[tid] = s[tid] - v;
}

__global__ __launch_bounds__(256)
void scan3(int* __restrict__ row_off, const int* __restrict__ bsum,
           int* __restrict__ cursor, int n, int E)
{
  int i = blockIdx.x * 256 + threadIdx.x;
  if (i < n) {
    int o = row_off[i] + bsum[blockIdx.x];
    row_off[i] = o;
    cursor[i] = o;
  }
  if (i == 0) row_off[n] = E;
}

__global__ __launch_bounds__(256)
void fill_csr(const int* __restrict__ src, const int* __restrict__ dst,
              int* __restrict__ cursor, int* __restrict__ adj, int E)
{
  int e = blockIdx.x * 256 + threadIdx.x;
  if (e < E) {
    int pos = atomicAdd(&cursor[dst[e]], 1);
    adj[pos] = src[e];
  }
}

// ---------------------------------------------------------------------------
// Gather: t[i] = h[i] + sum_{j in adj[row_off[i]..row_off[i+1])} h[j]
// ---------------------------------------------------------------------------
__global__ __launch_bounds__(256)
void gather_add(const float* __restrict__ h, const int* __restrict__ row_off,
                const int* __restrict__ adj, float* __restrict__ t, int n)
{
  int g = threadIdx.x >> 5, lane = threadIdx.x & 31;
  int node = blockIdx.x * 8 + g;
  if (node >= n) return;
  int beg = row_off[node], end = row_off[node + 1];

  float4 acc = *(const float4*)(h + (long long)node * NF + lane * 4);
  for (int base = beg; base < end; base += 32) {
    int cnt = min(32, end - base);
    int myadj = (lane < cnt) ? adj[base + lane] : 0;
    for (int k = 0; k < cnt; ++k) {
      int s = __shfl(myadj, k, 32);
      float4 v = *(const float4*)(h + (long long)s * NF + lane * 4);
      acc.x += v.x; acc.y += v.y; acc.z += v.z; acc.w += v.w;
    }
  }
  *(float4*)(t + (long long)node * NF + lane * 4) = acc;
}

// ---------------------------------------------------------------------------
// Tiled GEMM: out = relu(in @ W + bias).  64 rows x 128 cols per block,
// 256 threads; thread (rg=tid>>5, cg=tid&31) owns rows rg*8..+7, cols cg*4..+3.
// LDS: rA[64][128] row-major A tile (32 KB), Wt[32][128] K-tile (16 KB).
// A-reads in compute are same-address broadcasts; W-reads contiguous b128.
// ---------------------------------------------------------------------------
__global__ __launch_bounds__(256)
void gemm_tiled(const float* __restrict__ in, const float* __restrict__ W,
                const float* __restrict__ bias, float* __restrict__ out, int nrows)
{
  __shared__ float rA[BM][NF];    // [r][k]
  __shared__ float Wt[32][NF];    // [k][j]

  const int tid = threadIdx.x;
  const int cg = tid & 31;
  const int rg = tid >> 5;
  const int row0 = blockIdx.x * BM;

  // stage A tile: 64 rows * 32 float4 = 2048 float4; 8 per thread
  #pragma unroll
  for (int i = 0; i < 8; ++i) {
    int fidx = tid + 256 * i;       // 0..2047
    int r  = fidx >> 5;             // 0..63
    int c4 = fidx & 31;             // 0..31
    int row = row0 + r;
    float4 v = make_float4(0.f, 0.f, 0.f, 0.f);
    if (row < nrows) v = *(const float4*)(in + (long long)row * NF + c4 * 4);
    *(float4*)&rA[r][c4 * 4] = v;
  }

  float acc[8][4];
  #pragma unroll
  for (int rr = 0; rr < 8; ++rr)
    #pragma unroll
    for (int j = 0; j < 4; ++j) acc[rr][j] = 0.f;

  for (int kt = 0; kt < NF; kt += 32) {
    __syncthreads();                 // Wt safe to overwrite; also covers rA staging
    #pragma unroll
    for (int i = 0; i < 4; ++i) {
      int fidx = tid + 256 * i;      // 0..1023
      int k  = fidx >> 5;            // 0..31
      int c4 = fidx & 31;
      *(float4*)&Wt[k][c4 * 4] = *(const float4*)(W + (long long)(kt + k) * NF + c4 * 4);
    }
    __syncthreads();
    #pragma unroll
    for (int kc = 0; kc < 32; kc += 4) {
      float4 a[8];
      #pragma unroll
      for (int rr = 0; rr < 8; ++rr)
        a[rr] = *(const float4*)&rA[rg * 8 + rr][kt + kc];
      #pragma unroll
      for (int i = 0; i < 4; ++i) {
        float4 w = *(const float4*)&Wt[kc + i][cg * 4];
        #pragma unroll
        for (int rr = 0; rr < 8; ++rr) {
          float av = (i == 0) ? a[rr].x : (i == 1) ? a[rr].y
                   : (i == 2) ? a[rr].z : a[rr].w;
          acc[rr][0] = fmaf(av, w.x, acc[rr][0]);
          acc[rr][1] = fmaf(av, w.y, acc[rr][1]);
          acc[rr][2] = fmaf(av, w.z, acc[rr][2]);
          acc[rr][3] = fmaf(av, w.w, acc[rr][3]);
        }
      }
    }
  }

  const float4 bv = *(const float4*)(bias + cg * 4);
  #pragma unroll
  for (int rr = 0; rr < 8; ++rr) {
    int row = row0 + rg * 8 + rr;
    if (row < nrows) {
      float4 o;
      o.x = fmaxf(acc[rr][0] + bv.x, 0.f);
      o.y = fmaxf(acc[rr][1] + bv.y, 0.f);
      o.z = fmaxf(acc[rr][2] + bv.z, 0.f);
      o.w = fmaxf(acc[rr][3] + bv.w, 0.f);
      *(float4*)(out + (long long)row * NF + cg * 4) = o;
    }
  }
}

// ---------------------------------------------------------------------------
// BN stats stage 1: deterministic fp64 partials (128 blocks x 256 thr)
// ---------------------------------------------------------------------------
__global__ __launch_bounds__(256)
void bn_stats_partial(const float* __restrict__ v, double* __restrict__ part, int nrows)
{
  __shared__ double sd[2][NF], sq[2][NF];
  int tid = threadIdx.x;
  int c = tid & 127, ty = tid >> 7;
  int b = blockIdx.x;
  double s = 0.0, s2 = 0.0;
  for (long long r = b * 2 + ty; r < nrows; r += 256) {
    double x = (double)v[r * NF + c];
    s  += x;
    s2 += x * x;
  }
  sd[ty][c] = s;
  sq[ty][c] = s2;
  __syncthreads();
  if (ty == 0) {
    part[b * NF + c]            = sd[0][c] + sd[1][c];
    part[128 * NF + b * NF + c] = sq[0][c] + sq[1][c];
  }
}

__global__ void bn_stats_final(const double* __restrict__ part,
                               const float* __restrict__ gamma,
                               const float* __restrict__ beta,
                               float* __restrict__ ss, int nrows)
{
  int c = threadIdx.x;
  double s = 0.0, s2 = 0.0;
  for (int b = 0; b < 128; ++b) {
    s  += part[b * NF + c];
    s2 += part[128 * NF + b * NF + c];
  }
  double invN = 1.0 / (double)nrows;
  double mu  = s * invN;
  double var = s2 * invN - mu * mu;
  double sc  = (double)gamma[c] / sqrt(var + (double)BN_EPS_C);
  ss[c]      = (float)sc;
  ss[NF + c] = (float)((double)beta[c] - mu * sc);
}

__global__ __launch_bounds__(256)
void bn_apply(const float* __restrict__ v, const float* __restrict__ ss,
              float* __restrict__ out, int nrows)
{
  long long i = (long long)blockIdx.x * 256 + threadIdx.x;  // float4 index
  long long total = (long long)nrows * (NF / 4);
  if (i >= total) return;
  int c = (int)(i & 31) * 4;
  float4 val = ((const float4*)v)[i];
  float4 o;
  o.x = fmaf(val.x, ss[c + 0], ss[NF + c + 0]);
  o.y = fmaf(val.y, ss[c + 1], ss[NF + c + 1]);
  o.z = fmaf(val.z, ss[c + 2], ss[NF + c + 2]);
  o.w = fmaf(val.w, ss[c + 3], ss[NF + c + 3]);
  ((float4*)out)[i] = o;
}

__global__ void copy_batch(const int* __restrict__ b, float* __restrict__ o, int n)
{
  int i = blockIdx.x * 256 + threadIdx.x;
  if (i < n) o[i] = (float)b[i];
}

// ---------------------------------------------------------------------------
extern "C" void kernel_launch(void* const* d_in, const int* in_sizes, int n_in,
                              void* d_out, int out_size, void* d_ws, size_t ws_size,
                              hipStream_t stream)
{
  const float* x     = (const float*)d_in[0];
  const int*   ei    = (const int*)  d_in[1];
  const int*   batch = (const int*)  d_in[2];
  const float* W1    = (const float*)d_in[3];
  const float* b1    = (const float*)d_in[4];
  const float* W2    = (const float*)d_in[5];
  const float* b2    = (const float*)d_in[6];
  const float* gamma = (const float*)d_in[7];
  const float* beta  = (const float*)d_in[8];

  const int N = in_sizes[2];
  const int E = in_sizes[1] / 2;
  const int L = in_sizes[4] / NF;

  const int* src = ei;
  const int* dst = ei + E;

  // workspace layout
  float*  t       = (float*)d_ws;                      // N*NF
  double* part    = (double*)(t + (size_t)N * NF);     // 2*128*128
  float*  ss      = (float*)(part + 2 * 128 * NF);     // 256
  int*    count   = (int*)(ss + 256);                  // N
  int*    row_off = count + N;                         // N+1
  int*    cursor  = row_off + (N + 1);                 // N
  int*    adj     = cursor + N;                        // E
  int*    bsum    = adj + E;                           // 256

  float* hbuf = (float*)d_out;                         // N*NF ping-pong + final
  float* outBatch = hbuf + (size_t)N * NF;

  const long long n4 = (long long)N * (NF / 4);
  const int cpBlocks   = (int)((n4 + 255) / 256);
  const int eBlocks    = (E + 255) / 256;
  const int nBlocks256 = (N + 255) / 256;
  const int gthBlocks  = (N + 7) / 8;
  const int gemmBlocks = (N + BM - 1) / BM;

  // ---- CSR build (once, reused by all layers) ----
  zero_counts<<<nBlocks256, 256, 0, stream>>>(count, N);
  hist_dst<<<eBlocks, 256, 0, stream>>>(dst, count, E);
  scan1<<<nBlocks256, 256, 0, stream>>>(count, row_off, bsum, N);
  scan2<<<1, 256, 0, stream>>>(bsum, nBlocks256);
  scan3<<<nBlocks256, 256, 0, stream>>>(row_off, bsum, cursor, N, E);
  fill_csr<<<eBlocks, 256, 0, stream>>>(src, dst, cursor, adj, E);

  // ---- layers ----
  const float* h = x;
  for (int l = 0; l < L; ++l) {
    gather_add<<<gthBlocks, 256, 0, stream>>>(h, row_off, adj, t, N);
    gemm_tiled<<<gemmBlocks, 256, 0, stream>>>(t, W1 + (size_t)l * NF * NF,
                                               b1 + (size_t)l * NF, hbuf, N);
    gemm_tiled<<<gemmBlocks, 256, 0, stream>>>(hbuf, W2 + (size_t)l * NF * NF,
                                               b2 + (size_t)l * NF, t, N);
    bn_stats_partial<<<128, 256, 0, stream>>>(t, part, N);
    bn_stats_final<<<1, NF, 0, stream>>>(part, gamma + (size_t)l * NF,
                                         beta + (size_t)l * NF, ss, N);
    bn_apply<<<cpBlocks, 256, 0, stream>>>(t, ss, hbuf, N);
    h = hbuf;
  }

  copy_batch<<<nBlocks256, 256, 0, stream>>>(batch, outBatch, N);
}

// Round 6
// 578.261 us; speedup vs baseline: 8.3718x; 1.1933x over previous
//
#include <hip/hip_runtime.h>
#include <hip/hip_bf16.h>

constexpr int NF = 128;
constexpr int BM = 64;               // rows per GEMM block
constexpr float BN_EPS_C = 1e-5f;

// ---------------------------------------------------------------------------
// CSR build: histogram -> 2-level exclusive scan -> fill (counting sort by dst)
// ---------------------------------------------------------------------------
__global__ __launch_bounds__(256)
void zero_counts(int* __restrict__ count, int n)
{
  int i = blockIdx.x * 256 + threadIdx.x;
  if (i < n) count[i] = 0;
}

__global__ __launch_bounds__(256)
void hist_dst(const int* __restrict__ dst, int* __restrict__ count, int E)
{
  int e = blockIdx.x * 256 + threadIdx.x;
  if (e < E) atomicAdd(&count[dst[e]], 1);
}

__global__ __launch_bounds__(256)
void scan1(const int* __restrict__ count, int* __restrict__ excl,
           int* __restrict__ bsum, int n)
{
  __shared__ int s[256];
  int tid = threadIdx.x;
  int i = blockIdx.x * 256 + tid;
  int v = (i < n) ? count[i] : 0;
  s[tid] = v;
  __syncthreads();
  #pragma unroll
  for (int d = 1; d < 256; d <<= 1) {
    int t = (tid >= d) ? s[tid - d] : 0;
    __syncthreads();
    s[tid] += t;
    __syncthreads();
  }
  if (i < n) excl[i] = s[tid] - v;
  if (tid == 255) bsum[blockIdx.x] = s[255];
}

__global__ __launch_bounds__(256)
void scan2(int* __restrict__ bsum, int nb)
{
  __shared__ int s[256];
  int tid = threadIdx.x;
  int v = (tid < nb) ? bsum[tid] : 0;
  s[tid] = v;
  __syncthreads();
  #pragma unroll
  for (int d = 1; d < 256; d <<= 1) {
    int t = (tid >= d) ? s[tid - d] : 0;
    __syncthreads();
    s[tid] += t;
    __syncthreads();
  }
  if (tid < nb) bsum[tid] = s[tid] - v;
}

__global__ __launch_bounds__(256)
void scan3(int* __restrict__ row_off, const int* __restrict__ bsum,
           int* __restrict__ cursor, int n, int E)
{
  int i = blockIdx.x * 256 + threadIdx.x;
  if (i < n) {
    int o = row_off[i] + bsum[blockIdx.x];
    row_off[i] = o;
    cursor[i] = o;
  }
  if (i == 0) row_off[n] = E;
}

__global__ __launch_bounds__(256)
void fill_csr(const int* __restrict__ src, const int* __restrict__ dst,
              int* __restrict__ cursor, int* __restrict__ adj, int E)
{
  int e = blockIdx.x * 256 + threadIdx.x;
  if (e < E) {
    int pos = atomicAdd(&cursor[dst[e]], 1);
    adj[pos] = src[e];
  }
}

// ---------------------------------------------------------------------------
// Gather (+optional fused BN of the PREVIOUS layer via affine identity):
//   raw:  t[i] = h[i] + sum_j h[j]
//   BN:   t[i] = BN(v[i]) + sum_j BN(v[j]) = sc*(v[i]+sum v[j]) + (deg+1)*sh
// ---------------------------------------------------------------------------
template<bool BN>
__global__ __launch_bounds__(256)
void gather_add(const float* __restrict__ h, const int* __restrict__ row_off,
                const int* __restrict__ adj, const float* __restrict__ ss,
                float* __restrict__ t, int n)
{
  int g = threadIdx.x >> 5, lane = threadIdx.x & 31;
  int node = blockIdx.x * 8 + g;
  if (node >= n) return;
  int beg = row_off[node], end = row_off[node + 1];

  float4 acc = *(const float4*)(h + (long long)node * NF + lane * 4);
  for (int base = beg; base < end; base += 32) {
    int cnt = min(32, end - base);
    int myadj = (lane < cnt) ? adj[base + lane] : 0;
    for (int k = 0; k < cnt; ++k) {
      int s = __shfl(myadj, k, 32);
      float4 v = *(const float4*)(h + (long long)s * NF + lane * 4);
      acc.x += v.x; acc.y += v.y; acc.z += v.z; acc.w += v.w;
    }
  }
  if (BN) {
    float4 sc = *(const float4*)(ss + lane * 4);
    float4 sh = *(const float4*)(ss + NF + lane * 4);
    float dp1 = (float)(end - beg + 1);
    acc.x = fmaf(acc.x, sc.x, dp1 * sh.x);
    acc.y = fmaf(acc.y, sc.y, dp1 * sh.y);
    acc.z = fmaf(acc.z, sc.z, dp1 * sh.z);
    acc.w = fmaf(acc.w, sc.w, dp1 * sh.w);
  }
  *(float4*)(t + (long long)node * NF + lane * 4) = acc;
}

// ---------------------------------------------------------------------------
// Fused MLP: v = relu(relu(in@W1+b1)@W2+b2), + per-block fp64 BN partials.
// 64 rows x 128 cols per block, 256 threads; thread (rg,cg) owns 8 rows x 4 cols.
// LDS: rA[64][128] A tile then reused as u tile; Wt[32][128] K-tile, reused as
// fp64 reduction scratch (exactly 2048 doubles) in the epilogue.
// ---------------------------------------------------------------------------
__global__ __launch_bounds__(256)
void gemm12(const float* __restrict__ in,
            const float* __restrict__ W1, const float* __restrict__ b1,
            const float* __restrict__ W2, const float* __restrict__ b2,
            float* __restrict__ out, double* __restrict__ part,
            int nrows, int nblk)
{
  __shared__ float rA[BM][NF];    // A tile, later u tile
  __shared__ float Wt[32][NF];    // W K-tile, later fp64 reduce scratch

  const int tid = threadIdx.x;
  const int cg = tid & 31;
  const int rg = tid >> 5;
  const int row0 = blockIdx.x * BM;

  // stage A tile
  #pragma unroll
  for (int i = 0; i < 8; ++i) {
    int fidx = tid + 256 * i;
    int r  = fidx >> 5;
    int c4 = fidx & 31;
    int row = row0 + r;
    float4 v = make_float4(0.f, 0.f, 0.f, 0.f);
    if (row < nrows) v = *(const float4*)(in + (long long)row * NF + c4 * 4);
    *(float4*)&rA[r][c4 * 4] = v;
  }

  float acc[8][4];
  #pragma unroll
  for (int rr = 0; rr < 8; ++rr)
    #pragma unroll
    for (int j = 0; j < 4; ++j) acc[rr][j] = 0.f;

  // ---- GEMM1 ----
  for (int kt = 0; kt < NF; kt += 32) {
    __syncthreads();
    #pragma unroll
    for (int i = 0; i < 4; ++i) {
      int fidx = tid + 256 * i;
      int k  = fidx >> 5;
      int c4 = fidx & 31;
      *(float4*)&Wt[k][c4 * 4] = *(const float4*)(W1 + (long long)(kt + k) * NF + c4 * 4);
    }
    __syncthreads();
    #pragma unroll
    for (int kc = 0; kc < 32; kc += 4) {
      float4 a[8];
      #pragma unroll
      for (int rr = 0; rr < 8; ++rr)
        a[rr] = *(const float4*)&rA[rg * 8 + rr][kt + kc];
      #pragma unroll
      for (int i = 0; i < 4; ++i) {
        float4 w = *(const float4*)&Wt[kc + i][cg * 4];
        #pragma unroll
        for (int rr = 0; rr < 8; ++rr) {
          float av = (i == 0) ? a[rr].x : (i == 1) ? a[rr].y
                   : (i == 2) ? a[rr].z : a[rr].w;
          acc[rr][0] = fmaf(av, w.x, acc[rr][0]);
          acc[rr][1] = fmaf(av, w.y, acc[rr][1]);
          acc[rr][2] = fmaf(av, w.z, acc[rr][2]);
          acc[rr][3] = fmaf(av, w.w, acc[rr][3]);
        }
      }
    }
  }

  // u = relu(acc + b1); write into rA (dead) as the GEMM2 A-tile
  const float4 bv1 = *(const float4*)(b1 + cg * 4);
  float u[8][4];
  #pragma unroll
  for (int rr = 0; rr < 8; ++rr) {
    u[rr][0] = fmaxf(acc[rr][0] + bv1.x, 0.f);
    u[rr][1] = fmaxf(acc[rr][1] + bv1.y, 0.f);
    u[rr][2] = fmaxf(acc[rr][2] + bv1.z, 0.f);
    u[rr][3] = fmaxf(acc[rr][3] + bv1.w, 0.f);
  }
  __syncthreads();                 // all reads of rA/Wt done
  #pragma unroll
  for (int rr = 0; rr < 8; ++rr)
    *(float4*)&rA[rg * 8 + rr][cg * 4] = *(float4*)u[rr];

  #pragma unroll
  for (int rr = 0; rr < 8; ++rr)
    #pragma unroll
    for (int j = 0; j < 4; ++j) acc[rr][j] = 0.f;

  // ---- GEMM2 ----
  for (int kt = 0; kt < NF; kt += 32) {
    __syncthreads();               // uA writes visible (first iter); Wt reads done (later)
    #pragma unroll
    for (int i = 0; i < 4; ++i) {
      int fidx = tid + 256 * i;
      int k  = fidx >> 5;
      int c4 = fidx & 31;
      *(float4*)&Wt[k][c4 * 4] = *(const float4*)(W2 + (long long)(kt + k) * NF + c4 * 4);
    }
    __syncthreads();
    #pragma unroll
    for (int kc = 0; kc < 32; kc += 4) {
      float4 a[8];
      #pragma unroll
      for (int rr = 0; rr < 8; ++rr)
        a[rr] = *(const float4*)&rA[rg * 8 + rr][kt + kc];
      #pragma unroll
      for (int i = 0; i < 4; ++i) {
        float4 w = *(const float4*)&Wt[kc + i][cg * 4];
        #pragma unroll
        for (int rr = 0; rr < 8; ++rr) {
          float av = (i == 0) ? a[rr].x : (i == 1) ? a[rr].y
                   : (i == 2) ? a[rr].z : a[rr].w;
          acc[rr][0] = fmaf(av, w.x, acc[rr][0]);
          acc[rr][1] = fmaf(av, w.y, acc[rr][1]);
          acc[rr][2] = fmaf(av, w.z, acc[rr][2]);
          acc[rr][3] = fmaf(av, w.w, acc[rr][3]);
        }
      }
    }
  }

  // epilogue: v = relu(acc + b2) -> global; fp64 per-block BN partials
  const float4 bv2 = *(const float4*)(b2 + cg * 4);
  double ts[4] = {0.0, 0.0, 0.0, 0.0};
  double tq[4] = {0.0, 0.0, 0.0, 0.0};
  #pragma unroll
  for (int rr = 0; rr < 8; ++rr) {
    int row = row0 + rg * 8 + rr;
    if (row < nrows) {
      float4 o;
      o.x = fmaxf(acc[rr][0] + bv2.x, 0.f);
      o.y = fmaxf(acc[rr][1] + bv2.y, 0.f);
      o.z = fmaxf(acc[rr][2] + bv2.z, 0.f);
      o.w = fmaxf(acc[rr][3] + bv2.w, 0.f);
      *(float4*)(out + (long long)row * NF + cg * 4) = o;
      ts[0] += (double)o.x; tq[0] += (double)o.x * o.x;
      ts[1] += (double)o.y; tq[1] += (double)o.y * o.y;
      ts[2] += (double)o.z; tq[2] += (double)o.z * o.z;
      ts[3] += (double)o.w; tq[3] += (double)o.w * o.w;
    }
  }

  __syncthreads();                 // done with Wt as W2 tile
  double* red = (double*)&Wt[0][0];   // 2048 doubles: [0..1023]=sum, [1024..2047]=sumsq
  #pragma unroll
  for (int j = 0; j < 4; ++j) {
    red[rg * NF + cg * 4 + j]        = ts[j];
    red[1024 + rg * NF + cg * 4 + j] = tq[j];
  }
  __syncthreads();
  if (rg == 0) {
    #pragma unroll
    for (int j = 0; j < 4; ++j) {
      int c = cg * 4 + j;
      double s = 0.0, s2 = 0.0;
      #pragma unroll
      for (int g = 0; g < 8; ++g) {
        s  += red[g * NF + c];
        s2 += red[1024 + g * NF + c];
      }
      part[(long long)blockIdx.x * NF + c]                      = s;
      part[(long long)nblk * NF + (long long)blockIdx.x * NF + c] = s2;
    }
  }
}

// ---------------------------------------------------------------------------
// BN finalize: sum nblk fp64 partials -> scale/shift. 1024 thr: 8 chunks x 128 cols.
// ---------------------------------------------------------------------------
__global__ __launch_bounds__(1024)
void bn_stats_final(const double* __restrict__ part,
                    const float* __restrict__ gamma,
                    const float* __restrict__ beta,
                    float* __restrict__ ss, int nrows, int nblk)
{
  __shared__ double red[2][8][NF];
  int c = threadIdx.x & 127;
  int ch = threadIdx.x >> 7;           // 0..7
  int chunk = (nblk + 7) / 8;
  int b0 = ch * chunk, b1 = min(nblk, b0 + chunk);
  double s = 0.0, s2 = 0.0;
  for (int b = b0; b < b1; ++b) {
    s  += part[(long long)b * NF + c];
    s2 += part[(long long)nblk * NF + (long long)b * NF + c];
  }
  red[0][ch][c] = s;
  red[1][ch][c] = s2;
  __syncthreads();
  if (ch == 0) {
    double ts = 0.0, tq = 0.0;
    #pragma unroll
    for (int g = 0; g < 8; ++g) { ts += red[0][g][c]; tq += red[1][g][c]; }
    double invN = 1.0 / (double)nrows;
    double mu  = ts * invN;
    double var = tq * invN - mu * mu;
    double sc  = (double)gamma[c] / sqrt(var + (double)BN_EPS_C);
    ss[c]      = (float)sc;
    ss[NF + c] = (float)((double)beta[c] - mu * sc);
  }
}

// ---------------------------------------------------------------------------
// BN apply (used once, final layer; in-place safe: same index read/write)
// ---------------------------------------------------------------------------
__global__ __launch_bounds__(256)
void bn_apply(const float* __restrict__ v, const float* __restrict__ ss,
              float* __restrict__ out, int nrows)
{
  long long i = (long long)blockIdx.x * 256 + threadIdx.x;
  long long total = (long long)nrows * (NF / 4);
  if (i >= total) return;
  int c = (int)(i & 31) * 4;
  float4 val = ((const float4*)v)[i];
  float4 o;
  o.x = fmaf(val.x, ss[c + 0], ss[NF + c + 0]);
  o.y = fmaf(val.y, ss[c + 1], ss[NF + c + 1]);
  o.z = fmaf(val.z, ss[c + 2], ss[NF + c + 2]);
  o.w = fmaf(val.w, ss[c + 3], ss[NF + c + 3]);
  ((float4*)out)[i] = o;
}

__global__ void copy_batch(const int* __restrict__ b, float* __restrict__ o, int n)
{
  int i = blockIdx.x * 256 + threadIdx.x;
  if (i < n) o[i] = (float)b[i];
}

// ---------------------------------------------------------------------------
extern "C" void kernel_launch(void* const* d_in, const int* in_sizes, int n_in,
                              void* d_out, int out_size, void* d_ws, size_t ws_size,
                              hipStream_t stream)
{
  const float* x     = (const float*)d_in[0];
  const int*   ei    = (const int*)  d_in[1];
  const int*   batch = (const int*)  d_in[2];
  const float* W1    = (const float*)d_in[3];
  const float* b1    = (const float*)d_in[4];
  const float* W2    = (const float*)d_in[5];
  const float* b2    = (const float*)d_in[6];
  const float* gamma = (const float*)d_in[7];
  const float* beta  = (const float*)d_in[8];

  const int N = in_sizes[2];
  const int E = in_sizes[1] / 2;
  const int L = in_sizes[4] / NF;

  const int* src = ei;
  const int* dst = ei + E;

  const int gemmBlocks = (N + BM - 1) / BM;

  // workspace layout
  float*  agg     = (float*)d_ws;                      // N*NF (gather output)
  double* part    = (double*)(agg + (size_t)N * NF);   // 2*gemmBlocks*NF
  float*  ss      = (float*)(part + 2 * (size_t)gemmBlocks * NF);  // 256
  int*    count   = (int*)(ss + 256);                  // N
  int*    row_off = count + N;                         // N+1
  int*    cursor  = row_off + (N + 1);                 // N
  int*    adj     = cursor + N;                        // E
  int*    bsum    = adj + E;                           // 256

  float* vbuf = (float*)d_out;                         // N*NF (v / final h)
  float* outBatch = vbuf + (size_t)N * NF;

  const long long n4 = (long long)N * (NF / 4);
  const int cpBlocks   = (int)((n4 + 255) / 256);
  const int eBlocks    = (E + 255) / 256;
  const int nBlocks256 = (N + 255) / 256;
  const int gthBlocks  = (N + 7) / 8;

  // ---- CSR build (once) ----
  zero_counts<<<nBlocks256, 256, 0, stream>>>(count, N);
  hist_dst<<<eBlocks, 256, 0, stream>>>(dst, count, E);
  scan1<<<nBlocks256, 256, 0, stream>>>(count, row_off, bsum, N);
  scan2<<<1, 256, 0, stream>>>(bsum, nBlocks256);
  scan3<<<nBlocks256, 256, 0, stream>>>(row_off, bsum, cursor, N, E);
  fill_csr<<<eBlocks, 256, 0, stream>>>(src, dst, cursor, adj, E);

  // ---- layers ----
  for (int l = 0; l < L; ++l) {
    if (l == 0)
      gather_add<false><<<gthBlocks, 256, 0, stream>>>(x, row_off, adj, nullptr, agg, N);
    else
      gather_add<true><<<gthBlocks, 256, 0, stream>>>(vbuf, row_off, adj, ss, agg, N);
    gemm12<<<gemmBlocks, 256, 0, stream>>>(
        agg, W1 + (size_t)l * NF * NF, b1 + (size_t)l * NF,
        W2 + (size_t)l * NF * NF, b2 + (size_t)l * NF,
        vbuf, part, N, gemmBlocks);
    bn_stats_final<<<1, 1024, 0, stream>>>(part, gamma + (size_t)l * NF,
                                           beta + (size_t)l * NF, ss, N, gemmBlocks);
  }

  // final: h = BN(v) in-place in d_out
  bn_apply<<<cpBlocks, 256, 0, stream>>>(vbuf, ss, vbuf, N);
  copy_batch<<<nBlocks256, 256, 0, stream>>>(batch, outBatch, N);
}

// Round 7
// 327.227 us; speedup vs baseline: 14.7943x; 1.7672x over previous
//
#include <hip/hip_runtime.h>
#include <hip/hip_bf16.h>

constexpr int NF = 128;
constexpr int BM = 128;              // rows per gemm12 block
constexpr float BN_EPS_C = 1e-5f;

typedef __attribute__((ext_vector_type(8))) short short8;   // 8 bf16 = 4 VGPR
typedef __attribute__((ext_vector_type(4))) float f32x4;    // MFMA acc

__device__ __forceinline__ float asfloat(unsigned int u) {
  union { unsigned int u; float f; } c; c.u = u; return c.f;
}
__device__ __forceinline__ unsigned short f2b(float f) {
  __hip_bfloat16 b = __float2bfloat16(f);           // RNE
  return *reinterpret_cast<unsigned short*>(&b);
}

// ---------------------------------------------------------------------------
// CSR build (unchanged, verified)
// ---------------------------------------------------------------------------
__global__ __launch_bounds__(256)
void zero_counts(int* __restrict__ count, int n)
{
  int i = blockIdx.x * 256 + threadIdx.x;
  if (i < n) count[i] = 0;
}

__global__ __launch_bounds__(256)
void hist_dst(const int* __restrict__ dst, int* __restrict__ count, int E)
{
  int e = blockIdx.x * 256 + threadIdx.x;
  if (e < E) atomicAdd(&count[dst[e]], 1);
}

__global__ __launch_bounds__(256)
void scan1(const int* __restrict__ count, int* __restrict__ excl,
           int* __restrict__ bsum, int n)
{
  __shared__ int s[256];
  int tid = threadIdx.x;
  int i = blockIdx.x * 256 + tid;
  int v = (i < n) ? count[i] : 0;
  s[tid] = v;
  __syncthreads();
  #pragma unroll
  for (int d = 1; d < 256; d <<= 1) {
    int t = (tid >= d) ? s[tid - d] : 0;
    __syncthreads();
    s[tid] += t;
    __syncthreads();
  }
  if (i < n) excl[i] = s[tid] - v;
  if (tid == 255) bsum[blockIdx.x] = s[255];
}

__global__ __launch_bounds__(256)
void scan2(int* __restrict__ bsum, int nb)
{
  __shared__ int s[256];
  int tid = threadIdx.x;
  int v = (tid < nb) ? bsum[tid] : 0;
  s[tid] = v;
  __syncthreads();
  #pragma unroll
  for (int d = 1; d < 256; d <<= 1) {
    int t = (tid >= d) ? s[tid - d] : 0;
    __syncthreads();
    s[tid] += t;
    __syncthreads();
  }
  if (tid < nb) bsum[tid] = s[tid] - v;
}

__global__ __launch_bounds__(256)
void scan3(int* __restrict__ row_off, const int* __restrict__ bsum,
           int* __restrict__ cursor, int n, int E)
{
  int i = blockIdx.x * 256 + threadIdx.x;
  if (i < n) {
    int o = row_off[i] + bsum[blockIdx.x];
    row_off[i] = o;
    cursor[i] = o;
  }
  if (i == 0) row_off[n] = E;
}

__global__ __launch_bounds__(256)
void fill_csr(const int* __restrict__ src, const int* __restrict__ dst,
              int* __restrict__ cursor, int* __restrict__ adj, int E)
{
  int e = blockIdx.x * 256 + threadIdx.x;
  if (e < E) {
    int pos = atomicAdd(&cursor[dst[e]], 1);
    adj[pos] = src[e];
  }
}

// ---------------------------------------------------------------------------
// W -> bf16 transposed: out[m][c][k] = bf16(W[m][k][c])  (one-time, tiny)
// ---------------------------------------------------------------------------
__global__ __launch_bounds__(256)
void w_to_bf16t(const float* __restrict__ W, unsigned short* __restrict__ out, int total)
{
  int idx = blockIdx.x * 256 + threadIdx.x;
  if (idx >= total) return;
  int m = idx >> 14, ck = idx & 16383, c = ck >> 7, k = ck & 127;
  out[idx] = f2b(W[m * 16384 + k * 128 + c]);
}

// ---------------------------------------------------------------------------
// Layer-0 gather: fp32 x in, bf16 agg out. 32 lanes/node.
// ---------------------------------------------------------------------------
__global__ __launch_bounds__(256)
void gather_x(const float* __restrict__ x, const int* __restrict__ row_off,
              const int* __restrict__ adj, unsigned short* __restrict__ agg, int n)
{
  int g = threadIdx.x >> 5, lane = threadIdx.x & 31;
  int node = blockIdx.x * 8 + g;
  if (node >= n) return;
  int beg = row_off[node], end = row_off[node + 1];
  float4 acc = *(const float4*)(x + (size_t)node * NF + lane * 4);
  for (int base = beg; base < end; base += 32) {
    int cnt = min(32, end - base);
    int my = (lane < cnt) ? adj[base + lane] : 0;
    for (int k = 0; k < cnt; ++k) {
      int s = __shfl(my, k, 32);
      float4 v = *(const float4*)(x + (size_t)s * NF + lane * 4);
      acc.x += v.x; acc.y += v.y; acc.z += v.z; acc.w += v.w;
    }
  }
  ushort4 o;
  o.x = f2b(acc.x); o.y = f2b(acc.y); o.z = f2b(acc.z); o.w = f2b(acc.w);
  *(ushort4*)(agg + (size_t)node * NF + lane * 4) = o;
}

// ---------------------------------------------------------------------------
// Layers 1..: gather from bf16 v with fused BN affine:
//   agg[i] = bf16( sc * (v[i] + sum_j v[j]) + (deg+1) * sh )
// 16 lanes/node, each lane owns 8 columns (one uint4 = 8 bf16).
// ---------------------------------------------------------------------------
__global__ __launch_bounds__(256)
void gather_bn(const unsigned short* __restrict__ h, const int* __restrict__ row_off,
               const int* __restrict__ adj, const float* __restrict__ ss,
               unsigned short* __restrict__ agg, int n)
{
  int g = threadIdx.x >> 4, lane = threadIdx.x & 15;
  int node = blockIdx.x * 16 + g;
  if (node >= n) return;
  int beg = row_off[node], end = row_off[node + 1];

  float acc[8];
  {
    uint4 v = *(const uint4*)(h + (size_t)node * NF + lane * 8);
    acc[0] = asfloat(v.x << 16); acc[1] = asfloat(v.x & 0xffff0000u);
    acc[2] = asfloat(v.y << 16); acc[3] = asfloat(v.y & 0xffff0000u);
    acc[4] = asfloat(v.z << 16); acc[5] = asfloat(v.z & 0xffff0000u);
    acc[6] = asfloat(v.w << 16); acc[7] = asfloat(v.w & 0xffff0000u);
  }
  for (int base = beg; base < end; base += 16) {
    int cnt = min(16, end - base);
    int my = (lane < cnt) ? adj[base + lane] : 0;
    for (int k = 0; k < cnt; ++k) {
      int s = __shfl(my, k, 16);
      uint4 v = *(const uint4*)(h + (size_t)s * NF + lane * 8);
      acc[0] += asfloat(v.x << 16); acc[1] += asfloat(v.x & 0xffff0000u);
      acc[2] += asfloat(v.y << 16); acc[3] += asfloat(v.y & 0xffff0000u);
      acc[4] += asfloat(v.z << 16); acc[5] += asfloat(v.z & 0xffff0000u);
      acc[6] += asfloat(v.w << 16); acc[7] += asfloat(v.w & 0xffff0000u);
    }
  }
  float dp1 = (float)(end - beg + 1);
  unsigned short r[8];
  #pragma unroll
  for (int j = 0; j < 8; ++j) {
    float sc = ss[lane * 8 + j];
    float sh = ss[NF + lane * 8 + j];
    r[j] = f2b(fmaf(acc[j], sc, dp1 * sh));
  }
  uint4 o;
  o.x = (unsigned)r[0] | ((unsigned)r[1] << 16);
  o.y = (unsigned)r[2] | ((unsigned)r[3] << 16);
  o.z = (unsigned)r[4] | ((unsigned)r[5] << 16);
  o.w = (unsigned)r[6] | ((unsigned)r[7] << 16);
  *(uint4*)(agg + (size_t)node * NF + lane * 8) = o;
}

// ---------------------------------------------------------------------------
// Fused MLP via MFMA bf16: v = relu(relu(agg@W1+b1)@W2+b2) + fp64 BN partials.
// Block: 128 rows x 128 cols, 256 thr = 4 waves; wave w owns rows [w*32,w*32+32).
// Per wave: 2 row-stripes (16) x 8 col-tiles (16) x 4 K-steps (32) MFMAs.
// LDS: Alds[128][128] bf16 (32KB, XOR-swizzled), Wlds[128][128] bf16 (32KB,
// holds W1^T then W2^T then fp64 stats scratch).
// Frag layouts (16x16x32): A lane l: row=l&15, k=(l>>4)*8+j ; B: col=l&15, same k.
// C/D: col=lane&15, row=(lane>>4)*4+reg  [guide m89, HW-verified].
// ---------------------------------------------------------------------------
template<bool LAST>
__global__ __launch_bounds__(256)
void gemm12(const unsigned short* __restrict__ agg,
            const unsigned short* __restrict__ w1t, const float* __restrict__ b1,
            const unsigned short* __restrict__ w2t, const float* __restrict__ b2,
            float* __restrict__ vout, unsigned short* __restrict__ vb16,
            double* __restrict__ part, int nrows, int nblk)
{
  __shared__ __align__(16) unsigned short Alds[BM * NF];
  __shared__ __align__(16) unsigned short Wlds[NF * NF];

  const int tid = threadIdx.x;
  const int wid = tid >> 6;
  const int l   = tid & 63;
  const int lhi = l >> 4;          // 0..3
  const int llo = l & 15;          // 0..15
  const int row0 = blockIdx.x * BM;

  // ---- stage A tile (bf16, swizzled) ----
  #pragma unroll
  for (int i = 0; i < 8; ++i) {
    int fidx = tid + 256 * i;      // 2048 chunks of 16B
    int r = fidx >> 4, c16 = fidx & 15;
    int grow = row0 + r;
    uint4 v = make_uint4(0u, 0u, 0u, 0u);
    if (grow < nrows) v = *(const uint4*)(agg + (size_t)grow * NF + c16 * 8);
    int off = r * 256 + ((c16 * 16) ^ ((r & 7) << 4));
    *(uint4*)((char*)Alds + off) = v;
  }
  // ---- stage W1^T tile ----
  #pragma unroll
  for (int i = 0; i < 8; ++i) {
    int fidx = tid + 256 * i;
    int r = fidx >> 4, c16 = fidx & 15;
    uint4 v = *(const uint4*)(w1t + (size_t)r * NF + c16 * 8);
    int off = r * 256 + ((c16 * 16) ^ ((r & 7) << 4));
    *(uint4*)((char*)Wlds + off) = v;
  }

  float b1v[8], b2v[8];
  #pragma unroll
  for (int c = 0; c < 8; ++c) {
    b1v[c] = b1[c * 16 + llo];
    b2v[c] = b2[c * 16 + llo];
  }

  f32x4 acc[2][8];
  #pragma unroll
  for (int s = 0; s < 2; ++s)
    #pragma unroll
    for (int c = 0; c < 8; ++c) acc[s][c] = (f32x4){0.f, 0.f, 0.f, 0.f};

  __syncthreads();

  // ---- GEMM1 ----
  #pragma unroll
  for (int t = 0; t < 4; ++t) {
    short8 af[2];
    #pragma unroll
    for (int s = 0; s < 2; ++s) {
      int r = wid * 32 + s * 16 + llo;
      int off = r * 256 + ((t * 64 + lhi * 16) ^ ((r & 7) << 4));
      af[s] = *(const short8*)((const char*)Alds + off);
    }
    #pragma unroll
    for (int c = 0; c < 8; ++c) {
      int wr = c * 16 + llo;
      int off = wr * 256 + ((t * 64 + lhi * 16) ^ ((wr & 7) << 4));
      short8 bf = *(const short8*)((const char*)Wlds + off);
      acc[0][c] = __builtin_amdgcn_mfma_f32_16x16x32_bf16(af[0], bf, acc[0][c], 0, 0, 0);
      acc[1][c] = __builtin_amdgcn_mfma_f32_16x16x32_bf16(af[1], bf, acc[1][c], 0, 0, 0);
    }
  }

  __syncthreads();                 // GEMM1 LDS reads complete

  // ---- u = relu(acc+b1) -> Alds (swizzled scalar bf16 writes) ----
  #pragma unroll
  for (int s = 0; s < 2; ++s)
    #pragma unroll
    for (int c = 0; c < 8; ++c) {
      int colg = c * 16 + llo;
      #pragma unroll
      for (int q = 0; q < 4; ++q) {
        int r = wid * 32 + s * 16 + lhi * 4 + q;
        float u = fmaxf(acc[s][c][q] + b1v[c], 0.f);
        int off = r * 256 + ((colg * 2) ^ ((r & 7) << 4));
        *(unsigned short*)((char*)Alds + off) = f2b(u);
      }
    }
  // ---- stage W2^T tile ----
  #pragma unroll
  for (int i = 0; i < 8; ++i) {
    int fidx = tid + 256 * i;
    int r = fidx >> 4, c16 = fidx & 15;
    uint4 v = *(const uint4*)(w2t + (size_t)r * NF + c16 * 8);
    int off = r * 256 + ((c16 * 16) ^ ((r & 7) << 4));
    *(uint4*)((char*)Wlds + off) = v;
  }
  #pragma unroll
  for (int s = 0; s < 2; ++s)
    #pragma unroll
    for (int c = 0; c < 8; ++c) acc[s][c] = (f32x4){0.f, 0.f, 0.f, 0.f};

  __syncthreads();

  // ---- GEMM2 ----
  #pragma unroll
  for (int t = 0; t < 4; ++t) {
    short8 af[2];
    #pragma unroll
    for (int s = 0; s < 2; ++s) {
      int r = wid * 32 + s * 16 + llo;
      int off = r * 256 + ((t * 64 + lhi * 16) ^ ((r & 7) << 4));
      af[s] = *(const short8*)((const char*)Alds + off);
    }
    #pragma unroll
    for (int c = 0; c < 8; ++c) {
      int wr = c * 16 + llo;
      int off = wr * 256 + ((t * 64 + lhi * 16) ^ ((wr & 7) << 4));
      short8 bf = *(const short8*)((const char*)Wlds + off);
      acc[0][c] = __builtin_amdgcn_mfma_f32_16x16x32_bf16(af[0], bf, acc[0][c], 0, 0, 0);
      acc[1][c] = __builtin_amdgcn_mfma_f32_16x16x32_bf16(af[1], bf, acc[1][c], 0, 0, 0);
    }
  }

  // ---- epilogue: v = relu(acc+b2); store; fp32 lane stats ----
  float ts[8] = {0.f, 0.f, 0.f, 0.f, 0.f, 0.f, 0.f, 0.f};
  float tq[8] = {0.f, 0.f, 0.f, 0.f, 0.f, 0.f, 0.f, 0.f};
  #pragma unroll
  for (int s = 0; s < 2; ++s)
    #pragma unroll
    for (int c = 0; c < 8; ++c) {
      int colg = c * 16 + llo;
      #pragma unroll
      for (int q = 0; q < 4; ++q) {
        int rloc = wid * 32 + s * 16 + lhi * 4 + q;
        int row = row0 + rloc;
        if (row < nrows) {
          float vv = fmaxf(acc[s][c][q] + b2v[c], 0.f);
          ts[c] += vv; tq[c] += vv * vv;
          if (LAST) vout[(size_t)row * NF + colg] = vv;
          else      vb16[(size_t)row * NF + colg] = f2b(vv);
        }
      }
    }

  __syncthreads();                 // GEMM2 LDS reads complete; Wlds -> fp64 scratch
  double* redS = (double*)Wlds;    // [16][128]
  double* redQ = redS + 16 * NF;   // [16][128]
  int prow = wid * 4 + lhi;
  #pragma unroll
  for (int c = 0; c < 8; ++c) {
    redS[prow * NF + c * 16 + llo] = (double)ts[c];
    redQ[prow * NF + c * 16 + llo] = (double)tq[c];
  }
  __syncthreads();
  if (tid < NF) {
    double s = 0.0;
    #pragma unroll
    for (int r = 0; r < 16; ++r) s += redS[r * NF + tid];
    part[(size_t)blockIdx.x * NF + tid] = s;
  } else {
    int c = tid - NF;
    double s = 0.0;
    #pragma unroll
    for (int r = 0; r < 16; ++r) s += redQ[r * NF + c];
    part[(size_t)nblk * NF + (size_t)blockIdx.x * NF + c] = s;
  }
}

// ---------------------------------------------------------------------------
// BN finalize: fp64 partial sums -> scale/shift (1 block, 1024 thr)
// ---------------------------------------------------------------------------
__global__ __launch_bounds__(1024)
void bn_stats_final(const double* __restrict__ part,
                    const float* __restrict__ gamma,
                    const float* __restrict__ beta,
                    float* __restrict__ ss, int nrows, int nblk)
{
  __shared__ double red[2][8][NF];
  int c = threadIdx.x & 127;
  int ch = threadIdx.x >> 7;
  int chunk = (nblk + 7) / 8;
  int b0 = ch * chunk, b1 = min(nblk, b0 + chunk);
  double s = 0.0, s2 = 0.0;
  for (int b = b0; b < b1; ++b) {
    s  += part[(size_t)b * NF + c];
    s2 += part[(size_t)nblk * NF + (size_t)b * NF + c];
  }
  red[0][ch][c] = s;
  red[1][ch][c] = s2;
  __syncthreads();
  if (ch == 0) {
    double ts = 0.0, tq = 0.0;
    #pragma unroll
    for (int g = 0; g < 8; ++g) { ts += red[0][g][c]; tq += red[1][g][c]; }
    double invN = 1.0 / (double)nrows;
    double mu  = ts * invN;
    double var = tq * invN - mu * mu;
    double sc  = (double)gamma[c] / sqrt(var + (double)BN_EPS_C);
    ss[c]      = (float)sc;
    ss[NF + c] = (float)((double)beta[c] - mu * sc);
  }
}

// ---------------------------------------------------------------------------
// Final BN apply on fp32 v (in-place in d_out)
// ---------------------------------------------------------------------------
__global__ __launch_bounds__(256)
void bn_apply(const float* __restrict__ v, const float* __restrict__ ss,
              float* __restrict__ out, int nrows)
{
  long long i = (long long)blockIdx.x * 256 + threadIdx.x;
  long long total = (long long)nrows * (NF / 4);
  if (i >= total) return;
  int c = (int)(i & 31) * 4;
  float4 val = ((const float4*)v)[i];
  float4 o;
  o.x = fmaf(val.x, ss[c + 0], ss[NF + c + 0]);
  o.y = fmaf(val.y, ss[c + 1], ss[NF + c + 1]);
  o.z = fmaf(val.z, ss[c + 2], ss[NF + c + 2]);
  o.w = fmaf(val.w, ss[c + 3], ss[NF + c + 3]);
  ((float4*)out)[i] = o;
}

__global__ void copy_batch(const int* __restrict__ b, float* __restrict__ o, int n)
{
  int i = blockIdx.x * 256 + threadIdx.x;
  if (i < n) o[i] = (float)b[i];
}

// ---------------------------------------------------------------------------
extern "C" void kernel_launch(void* const* d_in, const int* in_sizes, int n_in,
                              void* d_out, int out_size, void* d_ws, size_t ws_size,
                              hipStream_t stream)
{
  const float* x     = (const float*)d_in[0];
  const int*   ei    = (const int*)  d_in[1];
  const int*   batch = (const int*)  d_in[2];
  const float* W1    = (const float*)d_in[3];
  const float* b1    = (const float*)d_in[4];
  const float* W2    = (const float*)d_in[5];
  const float* b2    = (const float*)d_in[6];
  const float* gamma = (const float*)d_in[7];
  const float* beta  = (const float*)d_in[8];

  const int N = in_sizes[2];
  const int E = in_sizes[1] / 2;
  const int L = in_sizes[4] / NF;

  const int* src = ei;
  const int* dst = ei + E;

  const int nblk = (N + BM - 1) / BM;

  // workspace layout (16B-aligned tensors first)
  double* part = (double*)d_ws;                                 // 2*nblk*128
  float*  ss   = (float*)(part + 2 * (size_t)nblk * NF);        // 256
  unsigned short* aggb = (unsigned short*)(ss + 256);           // N*128 bf16
  unsigned short* vb   = aggb + (size_t)N * NF;                 // N*128 bf16
  unsigned short* wt   = vb + (size_t)N * NF;                   // 6*16384 bf16
  int* count   = (int*)(wt + 6 * 16384);                        // N
  int* row_off = count + N;                                     // N+1
  int* cursor  = row_off + (N + 1);                             // N
  int* adj     = cursor + N;                                    // E
  int* bsum    = adj + E;                                       // 256

  float* vbuf = (float*)d_out;                                  // N*128 fp32
  float* outBatch = vbuf + (size_t)N * NF;

  const int eBlocks    = (E + 255) / 256;
  const int nBlocks256 = (N + 255) / 256;
  const int bnBlocks   = (int)(((long long)N * (NF / 4) + 255) / 256);

  // ---- one-time weight prep + CSR build ----
  w_to_bf16t<<<(3 * 16384 + 255) / 256, 256, 0, stream>>>(W1, wt, 3 * 16384);
  w_to_bf16t<<<(3 * 16384 + 255) / 256, 256, 0, stream>>>(W2, wt + 3 * 16384, 3 * 16384);
  zero_counts<<<nBlocks256, 256, 0, stream>>>(count, N);
  hist_dst<<<eBlocks, 256, 0, stream>>>(dst, count, E);
  scan1<<<nBlocks256, 256, 0, stream>>>(count, row_off, bsum, N);
  scan2<<<1, 256, 0, stream>>>(bsum, nBlocks256);
  scan3<<<nBlocks256, 256, 0, stream>>>(row_off, bsum, cursor, N, E);
  fill_csr<<<eBlocks, 256, 0, stream>>>(src, dst, cursor, adj, E);

  // ---- layers ----
  for (int ly = 0; ly < L; ++ly) {
    if (ly == 0)
      gather_x<<<(N + 7) / 8, 256, 0, stream>>>(x, row_off, adj, aggb, N);
    else
      gather_bn<<<(N + 15) / 16, 256, 0, stream>>>(vb, row_off, adj, ss, aggb, N);

    const unsigned short* w1t = wt + (size_t)ly * 16384;
    const unsigned short* w2t = wt + (size_t)(3 + ly) * 16384;
    if (ly == L - 1)
      gemm12<true><<<nblk, 256, 0, stream>>>(aggb, w1t, b1 + ly * NF, w2t, b2 + ly * NF,
                                             vbuf, vb, part, N, nblk);
    else
      gemm12<false><<<nblk, 256, 0, stream>>>(aggb, w1t, b1 + ly * NF, w2t, b2 + ly * NF,
                                              vbuf, vb, part, N, nblk);
    bn_stats_final<<<1, 1024, 0, stream>>>(part, gamma + ly * NF, beta + ly * NF,
                                           ss, N, nblk);
  }

  // final: h = BN(v) in place, then batch
  bn_apply<<<bnBlocks, 256, 0, stream>>>(vbuf, ss, vbuf, N);
  copy_batch<<<nBlocks256, 256, 0, stream>>>(batch, outBatch, N);
}

// Round 8
// 315.219 us; speedup vs baseline: 15.3578x; 1.0381x over previous
//
#include <hip/hip_runtime.h>
#include <hip/hip_bf16.h>

constexpr int NF = 128;
constexpr int BM = 128;              // rows per gemm12 block
constexpr float BN_EPS_C = 1e-5f;

typedef __attribute__((ext_vector_type(8))) short short8;   // 8 bf16 = 4 VGPR
typedef __attribute__((ext_vector_type(4))) float f32x4;    // MFMA acc

__device__ __forceinline__ float asfloat(unsigned int u) {
  union { unsigned int u; float f; } c; c.u = u; return c.f;
}
__device__ __forceinline__ unsigned short f2b(float f) {
  __hip_bfloat16 b = __float2bfloat16(f);           // RNE
  return *reinterpret_cast<unsigned short*>(&b);
}
__device__ __forceinline__ void addbf8(float* acc, uint4 v) {
  acc[0] += asfloat(v.x << 16); acc[1] += asfloat(v.x & 0xffff0000u);
  acc[2] += asfloat(v.y << 16); acc[3] += asfloat(v.y & 0xffff0000u);
  acc[4] += asfloat(v.z << 16); acc[5] += asfloat(v.z & 0xffff0000u);
  acc[6] += asfloat(v.w << 16); acc[7] += asfloat(v.w & 0xffff0000u);
}

// ---------------------------------------------------------------------------
// CSR build (unchanged, verified)
// ---------------------------------------------------------------------------
__global__ __launch_bounds__(256)
void zero_counts(int* __restrict__ count, int n)
{
  int i = blockIdx.x * 256 + threadIdx.x;
  if (i < n) count[i] = 0;
}

__global__ __launch_bounds__(256)
void hist_dst(const int* __restrict__ dst, int* __restrict__ count, int E)
{
  int e = blockIdx.x * 256 + threadIdx.x;
  if (e < E) atomicAdd(&count[dst[e]], 1);
}

__global__ __launch_bounds__(256)
void scan1(const int* __restrict__ count, int* __restrict__ excl,
           int* __restrict__ bsum, int n)
{
  __shared__ int s[256];
  int tid = threadIdx.x;
  int i = blockIdx.x * 256 + tid;
  int v = (i < n) ? count[i] : 0;
  s[tid] = v;
  __syncthreads();
  #pragma unroll
  for (int d = 1; d < 256; d <<= 1) {
    int t = (tid >= d) ? s[tid - d] : 0;
    __syncthreads();
    s[tid] += t;
    __syncthreads();
  }
  if (i < n) excl[i] = s[tid] - v;
  if (tid == 255) bsum[blockIdx.x] = s[255];
}

__global__ __launch_bounds__(256)
void scan2(int* __restrict__ bsum, int nb)
{
  __shared__ int s[256];
  int tid = threadIdx.x;
  int v = (tid < nb) ? bsum[tid] : 0;
  s[tid] = v;
  __syncthreads();
  #pragma unroll
  for (int d = 1; d < 256; d <<= 1) {
    int t = (tid >= d) ? s[tid - d] : 0;
    __syncthreads();
    s[tid] += t;
    __syncthreads();
  }
  if (tid < nb) bsum[tid] = s[tid] - v;
}

__global__ __launch_bounds__(256)
void scan3(int* __restrict__ row_off, const int* __restrict__ bsum,
           int* __restrict__ cursor, int n, int E)
{
  int i = blockIdx.x * 256 + threadIdx.x;
  if (i < n) {
    int o = row_off[i] + bsum[blockIdx.x];
    row_off[i] = o;
    cursor[i] = o;
  }
  if (i == 0) row_off[n] = E;
}

__global__ __launch_bounds__(256)
void fill_csr(const int* __restrict__ src, const int* __restrict__ dst,
              int* __restrict__ cursor, int* __restrict__ adj, int E)
{
  int e = blockIdx.x * 256 + threadIdx.x;
  if (e < E) {
    int pos = atomicAdd(&cursor[dst[e]], 1);
    adj[pos] = src[e];
  }
}

// ---------------------------------------------------------------------------
// One-time converts
// ---------------------------------------------------------------------------
__global__ __launch_bounds__(256)
void w_to_bf16t(const float* __restrict__ W, unsigned short* __restrict__ out, int total)
{
  int idx = blockIdx.x * 256 + threadIdx.x;
  if (idx >= total) return;
  int m = idx >> 14, ck = idx & 16383, c = ck >> 7, k = ck & 127;
  out[idx] = f2b(W[m * 16384 + k * 128 + c]);
}

__global__ __launch_bounds__(256)
void x_to_bf16(const float* __restrict__ x, unsigned short* __restrict__ xb, long long n4)
{
  long long i = (long long)blockIdx.x * 256 + threadIdx.x;
  if (i >= n4) return;
  float4 v = ((const float4*)x)[i];
  ushort4 o;
  o.x = f2b(v.x); o.y = f2b(v.y); o.z = f2b(v.z); o.w = f2b(v.w);
  ((ushort4*)xb)[i] = o;
}

__global__ void init_ss(float* __restrict__ ss)
{
  ss[threadIdx.x] = (threadIdx.x < NF) ? 1.f : 0.f;   // identity affine for layer 0
}

// ---------------------------------------------------------------------------
// Gather + fused BN affine of the previous layer (identity for layer 0):
//   agg[i] = bf16( sc * (h[i] + sum_j h[j]) + (deg+1) * sh )
// One WAVE per node: 4 sub-groups of 16 lanes take neighbors e = beg+sub, +4...
// (uniform trip count within the wave), final shfl_xor(16/32) cross-sub reduce.
// ---------------------------------------------------------------------------
__global__ __launch_bounds__(256)
void gather_bn(const unsigned short* __restrict__ h, const int* __restrict__ row_off,
               const int* __restrict__ adj, const float* __restrict__ ss,
               unsigned short* __restrict__ agg, int n)
{
  int wv  = threadIdx.x >> 6;
  int l   = threadIdx.x & 63;
  int sub = l >> 4, llo = l & 15;
  int node = blockIdx.x * 4 + wv;
  if (node >= n) return;
  int beg = row_off[node], end = row_off[node + 1];

  float acc[8] = {0.f, 0.f, 0.f, 0.f, 0.f, 0.f, 0.f, 0.f};
  if (sub == 0)
    addbf8(acc, *(const uint4*)(h + (size_t)node * NF + llo * 8));   // self term

  for (int e = beg + sub; e < end; e += 4) {
    int s = adj[e];
    addbf8(acc, *(const uint4*)(h + (size_t)s * NF + llo * 8));
  }

  #pragma unroll
  for (int j = 0; j < 8; ++j) {
    acc[j] += __shfl_xor(acc[j], 16, 64);
    acc[j] += __shfl_xor(acc[j], 32, 64);
  }

  if (sub == 0) {
    float dp1 = (float)(end - beg + 1);
    unsigned short r[8];
    #pragma unroll
    for (int j = 0; j < 8; ++j) {
      float sc = ss[llo * 8 + j];
      float sh = ss[NF + llo * 8 + j];
      r[j] = f2b(fmaf(acc[j], sc, dp1 * sh));
    }
    uint4 o;
    o.x = (unsigned)r[0] | ((unsigned)r[1] << 16);
    o.y = (unsigned)r[2] | ((unsigned)r[3] << 16);
    o.z = (unsigned)r[4] | ((unsigned)r[5] << 16);
    o.w = (unsigned)r[6] | ((unsigned)r[7] << 16);
    *(uint4*)(agg + (size_t)node * NF + llo * 8) = o;
  }
}

// ---------------------------------------------------------------------------
// Fused MLP via MFMA bf16: v = relu(relu(agg@W1+b1)@W2+b2) + fp64 BN partials.
// Block: 128 rows x 128 cols, 4 waves; wave w owns rows [w*32, w*32+32).
// A tile in LDS (32KB, XOR-swizzled); B-fragments read DIRECTLY FROM GLOBAL
// (W^T is 32KB bf16, shared by all blocks -> L2-broadcast). After GEMM2 the
// A tile is reused as fp64 stats scratch (exactly 32KB).
// Frag mapping (16x16x32): A lane l: row=l&15, k=(l>>4)*8+j; B: col=l&15, same k.
// C/D: col=lane&15, row=(lane>>4)*4+reg  [guide m89, HW-verified].
// ---------------------------------------------------------------------------
template<bool LAST>
__global__ __launch_bounds__(256)
void gemm12(const unsigned short* __restrict__ agg,
            const unsigned short* __restrict__ w1t, const float* __restrict__ b1,
            const unsigned short* __restrict__ w2t, const float* __restrict__ b2,
            float* __restrict__ vout, unsigned short* __restrict__ vb16,
            double* __restrict__ part, int nrows, int nblk)
{
  __shared__ __align__(16) unsigned short Alds[BM * NF];   // 32 KB

  const int tid = threadIdx.x;
  const int wid = tid >> 6;
  const int l   = tid & 63;
  const int lhi = l >> 4;          // 0..3
  const int llo = l & 15;          // 0..15
  const int row0 = blockIdx.x * BM;

  // ---- stage A tile (bf16, swizzled) ----
  #pragma unroll
  for (int i = 0; i < 8; ++i) {
    int fidx = tid + 256 * i;      // 2048 chunks of 16B
    int r = fidx >> 4, c16 = fidx & 15;
    int grow = row0 + r;
    uint4 v = make_uint4(0u, 0u, 0u, 0u);
    if (grow < nrows) v = *(const uint4*)(agg + (size_t)grow * NF + c16 * 8);
    int off = r * 256 + ((c16 * 16) ^ ((r & 7) << 4));
    *(uint4*)((char*)Alds + off) = v;
  }

  float b1v[8], b2v[8];
  #pragma unroll
  for (int c = 0; c < 8; ++c) {
    b1v[c] = b1[c * 16 + llo];
    b2v[c] = b2[c * 16 + llo];
  }

  const short8* w1v = (const short8*)w1t;   // [128 rows][16 short8]
  const short8* w2v = (const short8*)w2t;

  f32x4 acc[2][8];
  #pragma unroll
  for (int s = 0; s < 2; ++s)
    #pragma unroll
    for (int c = 0; c < 8; ++c) acc[s][c] = (f32x4){0.f, 0.f, 0.f, 0.f};

  __syncthreads();

  // ---- GEMM1 ----
  #pragma unroll
  for (int t = 0; t < 4; ++t) {
    short8 af[2];
    #pragma unroll
    for (int s = 0; s < 2; ++s) {
      int r = wid * 32 + s * 16 + llo;
      int off = r * 256 + ((t * 64 + lhi * 16) ^ ((r & 7) << 4));
      af[s] = *(const short8*)((const char*)Alds + off);
    }
    #pragma unroll
    for (int c = 0; c < 8; ++c) {
      short8 bf = w1v[(c * 16 + llo) * 16 + t * 4 + lhi];
      acc[0][c] = __builtin_amdgcn_mfma_f32_16x16x32_bf16(af[0], bf, acc[0][c], 0, 0, 0);
      acc[1][c] = __builtin_amdgcn_mfma_f32_16x16x32_bf16(af[1], bf, acc[1][c], 0, 0, 0);
    }
  }

  __syncthreads();                 // GEMM1 LDS reads complete

  // ---- u = relu(acc+b1) -> Alds (swizzled scalar bf16 writes) ----
  #pragma unroll
  for (int s = 0; s < 2; ++s)
    #pragma unroll
    for (int c = 0; c < 8; ++c) {
      int colg = c * 16 + llo;
      #pragma unroll
      for (int q = 0; q < 4; ++q) {
        int r = wid * 32 + s * 16 + lhi * 4 + q;
        float u = fmaxf(acc[s][c][q] + b1v[c], 0.f);
        int off = r * 256 + ((colg * 2) ^ ((r & 7) << 4));
        *(unsigned short*)((char*)Alds + off) = f2b(u);
      }
    }
  #pragma unroll
  for (int s = 0; s < 2; ++s)
    #pragma unroll
    for (int c = 0; c < 8; ++c) acc[s][c] = (f32x4){0.f, 0.f, 0.f, 0.f};

  __syncthreads();                 // u visible

  // ---- GEMM2 ----
  #pragma unroll
  for (int t = 0; t < 4; ++t) {
    short8 af[2];
    #pragma unroll
    for (int s = 0; s < 2; ++s) {
      int r = wid * 32 + s * 16 + llo;
      int off = r * 256 + ((t * 64 + lhi * 16) ^ ((r & 7) << 4));
      af[s] = *(const short8*)((const char*)Alds + off);
    }
    #pragma unroll
    for (int c = 0; c < 8; ++c) {
      short8 bf = w2v[(c * 16 + llo) * 16 + t * 4 + lhi];
      acc[0][c] = __builtin_amdgcn_mfma_f32_16x16x32_bf16(af[0], bf, acc[0][c], 0, 0, 0);
      acc[1][c] = __builtin_amdgcn_mfma_f32_16x16x32_bf16(af[1], bf, acc[1][c], 0, 0, 0);
    }
  }

  // ---- epilogue: v = relu(acc+b2); store; fp32 lane stats ----
  float ts[8] = {0.f, 0.f, 0.f, 0.f, 0.f, 0.f, 0.f, 0.f};
  float tq[8] = {0.f, 0.f, 0.f, 0.f, 0.f, 0.f, 0.f, 0.f};
  #pragma unroll
  for (int s = 0; s < 2; ++s)
    #pragma unroll
    for (int c = 0; c < 8; ++c) {
      int colg = c * 16 + llo;
      #pragma unroll
      for (int q = 0; q < 4; ++q) {
        int rloc = wid * 32 + s * 16 + lhi * 4 + q;
        int row = row0 + rloc;
        if (row < nrows) {
          float vv = fmaxf(acc[s][c][q] + b2v[c], 0.f);
          ts[c] += vv; tq[c] += vv * vv;
          if (LAST) vout[(size_t)row * NF + colg] = vv;
          else      vb16[(size_t)row * NF + colg] = f2b(vv);
        }
      }
    }

  __syncthreads();                 // GEMM2 LDS reads complete; Alds -> fp64 scratch
  double* redS = (double*)Alds;    // [16][128]
  double* redQ = redS + 16 * NF;   // [16][128]  (total 32 KB = Alds exactly)
  int prow = wid * 4 + lhi;
  #pragma unroll
  for (int c = 0; c < 8; ++c) {
    redS[prow * NF + c * 16 + llo] = (double)ts[c];
    redQ[prow * NF + c * 16 + llo] = (double)tq[c];
  }
  __syncthreads();
  if (tid < NF) {
    double s = 0.0;
    #pragma unroll
    for (int r = 0; r < 16; ++r) s += redS[r * NF + tid];
    part[(size_t)blockIdx.x * NF + tid] = s;
  } else {
    int c = tid - NF;
    double s = 0.0;
    #pragma unroll
    for (int r = 0; r < 16; ++r) s += redQ[r * NF + c];
    part[(size_t)nblk * NF + (size_t)blockIdx.x * NF + c] = s;
  }
}

// ---------------------------------------------------------------------------
// BN finalize, parallel: 8 blocks x 1024 thr; block covers 16 columns.
// Deterministic fixed-order fp64 reduce (64 segments -> tree).
// ---------------------------------------------------------------------------
__global__ __launch_bounds__(1024)
void bn_stats_final(const double* __restrict__ part,
                    const float* __restrict__ gamma,
                    const float* __restrict__ beta,
                    float* __restrict__ ss, int nrows, int nblk)
{
  __shared__ double redS[64][17], redQ[64][17];   // padded: no bank conflicts
  int cl  = threadIdx.x & 15;
  int seg = threadIdx.x >> 4;          // 0..63
  int c = blockIdx.x * 16 + cl;
  double s = 0.0, s2 = 0.0;
  for (int b = seg; b < nblk; b += 64) {
    s  += part[(size_t)b * NF + c];
    s2 += part[(size_t)nblk * NF + (size_t)b * NF + c];
  }
  redS[seg][cl] = s;
  redQ[seg][cl] = s2;
  __syncthreads();
  #pragma unroll
  for (int d = 32; d >= 1; d >>= 1) {
    if (seg < d) {
      redS[seg][cl] += redS[seg + d][cl];
      redQ[seg][cl] += redQ[seg + d][cl];
    }
    __syncthreads();
  }
  if (seg == 0) {
    double invN = 1.0 / (double)nrows;
    double mu  = redS[0][cl] * invN;
    double var = redQ[0][cl] * invN - mu * mu;
    double sc  = (double)gamma[c] / sqrt(var + (double)BN_EPS_C);
    ss[c]      = (float)sc;
    ss[NF + c] = (float)((double)beta[c] - mu * sc);
  }
}

// ---------------------------------------------------------------------------
// Final BN apply on fp32 v (in-place in d_out)
// ---------------------------------------------------------------------------
__global__ __launch_bounds__(256)
void bn_apply(const float* __restrict__ v, const float* __restrict__ ss,
              float* __restrict__ out, int nrows)
{
  long long i = (long long)blockIdx.x * 256 + threadIdx.x;
  long long total = (long long)nrows * (NF / 4);
  if (i >= total) return;
  int c = (int)(i & 31) * 4;
  float4 val = ((const float4*)v)[i];
  float4 o;
  o.x = fmaf(val.x, ss[c + 0], ss[NF + c + 0]);
  o.y = fmaf(val.y, ss[c + 1], ss[NF + c + 1]);
  o.z = fmaf(val.z, ss[c + 2], ss[NF + c + 2]);
  o.w = fmaf(val.w, ss[c + 3], ss[NF + c + 3]);
  ((float4*)out)[i] = o;
}

__global__ void copy_batch(const int* __restrict__ b, float* __restrict__ o, int n)
{
  int i = blockIdx.x * 256 + threadIdx.x;
  if (i < n) o[i] = (float)b[i];
}

// ---------------------------------------------------------------------------
extern "C" void kernel_launch(void* const* d_in, const int* in_sizes, int n_in,
                              void* d_out, int out_size, void* d_ws, size_t ws_size,
                              hipStream_t stream)
{
  const float* x     = (const float*)d_in[0];
  const int*   ei    = (const int*)  d_in[1];
  const int*   batch = (const int*)  d_in[2];
  const float* W1    = (const float*)d_in[3];
  const float* b1    = (const float*)d_in[4];
  const float* W2    = (const float*)d_in[5];
  const float* b2    = (const float*)d_in[6];
  const float* gamma = (const float*)d_in[7];
  const float* beta  = (const float*)d_in[8];

  const int N = in_sizes[2];
  const int E = in_sizes[1] / 2;
  const int L = in_sizes[4] / NF;

  const int* src = ei;
  const int* dst = ei + E;

  const int nblk = (N + BM - 1) / BM;

  // workspace layout (16B-aligned tensors first)
  double* part = (double*)d_ws;                                 // 2*nblk*128
  float*  ss   = (float*)(part + 2 * (size_t)nblk * NF);        // 256
  unsigned short* aggb = (unsigned short*)(ss + 256);           // N*128 bf16
  unsigned short* vb   = aggb + (size_t)N * NF;                 // N*128 bf16
  unsigned short* wt   = vb + (size_t)N * NF;                   // 6*16384 bf16
  int* count   = (int*)(wt + 6 * 16384);                        // N
  int* row_off = count + N;                                     // N+1
  int* cursor  = row_off + (N + 1);                             // N
  int* adj     = cursor + N;                                    // E
  int* bsum    = adj + E;                                       // 256

  float* vbuf = (float*)d_out;                                  // N*128 fp32 (final)
  float* outBatch = vbuf + (size_t)N * NF;
  // xb lives in d_out's v-region (free until the LAST gemm12 writes vout)
  unsigned short* xb = (unsigned short*)vbuf;                   // N*128 bf16

  const int eBlocks    = (E + 255) / 256;
  const int nBlocks256 = (N + 255) / 256;
  const int bnBlocks   = (int)(((long long)N * (NF / 4) + 255) / 256);
  const long long x4   = (long long)N * NF / 4;

  // ---- one-time prep + CSR build ----
  x_to_bf16<<<(int)((x4 + 255) / 256), 256, 0, stream>>>(x, xb, x4);
  init_ss<<<1, 256, 0, stream>>>(ss);
  w_to_bf16t<<<(3 * 16384 + 255) / 256, 256, 0, stream>>>(W1, wt, 3 * 16384);
  w_to_bf16t<<<(3 * 16384 + 255) / 256, 256, 0, stream>>>(W2, wt + 3 * 16384, 3 * 16384);
  zero_counts<<<nBlocks256, 256, 0, stream>>>(count, N);
  hist_dst<<<eBlocks, 256, 0, stream>>>(dst, count, E);
  scan1<<<nBlocks256, 256, 0, stream>>>(count, row_off, bsum, N);
  scan2<<<1, 256, 0, stream>>>(bsum, nBlocks256);
  scan3<<<nBlocks256, 256, 0, stream>>>(row_off, bsum, cursor, N, E);
  fill_csr<<<eBlocks, 256, 0, stream>>>(src, dst, cursor, adj, E);

  // ---- layers ----
  for (int ly = 0; ly < L; ++ly) {
    const unsigned short* hsrc = (ly == 0) ? xb : vb;
    gather_bn<<<(N + 3) / 4, 256, 0, stream>>>(hsrc, row_off, adj, ss, aggb, N);

    const unsigned short* w1t = wt + (size_t)ly * 16384;
    const unsigned short* w2t = wt + (size_t)(3 + ly) * 16384;
    if (ly == L - 1)
      gemm12<true><<<nblk, 256, 0, stream>>>(aggb, w1t, b1 + ly * NF, w2t, b2 + ly * NF,
                                             vbuf, vb, part, N, nblk);
    else
      gemm12<false><<<nblk, 256, 0, stream>>>(aggb, w1t, b1 + ly * NF, w2t, b2 + ly * NF,
                                              vbuf, vb, part, N, nblk);
    bn_stats_final<<<8, 1024, 0, stream>>>(part, gamma + ly * NF, beta + ly * NF,
                                           ss, N, nblk);
  }

  // final: h = BN(v) in place, then batch
  bn_apply<<<bnBlocks, 256, 0, stream>>>(vbuf, ss, vbuf, N);
  copy_batch<<<nBlocks256, 256, 0, stream>>>(batch, outBatch, N);
}

// Round 9
// 249.091 us; speedup vs baseline: 19.4350x; 1.2655x over previous
//
#include <hip/hip_runtime.h>
#include <hip/hip_bf16.h>

constexpr int NF = 128;
constexpr int BM = 128;              // rows per gemm12 block
constexpr int SORT_CHUNK = 4096;     // edges per p1 block (256 thr x 16)
constexpr float BN_EPS_C = 1e-5f;

typedef __attribute__((ext_vector_type(8))) short short8;   // 8 bf16 = 4 VGPR
typedef __attribute__((ext_vector_type(4))) float f32x4;    // MFMA acc

__device__ __forceinline__ float asfloat(unsigned int u) {
  union { unsigned int u; float f; } c; c.u = u; return c.f;
}
__device__ __forceinline__ unsigned short f2b(float f) {
  __hip_bfloat16 b = __float2bfloat16(f);           // RNE
  return *reinterpret_cast<unsigned short*>(&b);
}
__device__ __forceinline__ void addbf8(float* acc, uint4 v) {
  acc[0] += asfloat(v.x << 16); acc[1] += asfloat(v.x & 0xffff0000u);
  acc[2] += asfloat(v.y << 16); acc[3] += asfloat(v.y & 0xffff0000u);
  acc[4] += asfloat(v.z << 16); acc[5] += asfloat(v.z & 0xffff0000u);
  acc[6] += asfloat(v.w << 16); acc[7] += asfloat(v.w & 0xffff0000u);
}

// ---------------------------------------------------------------------------
// CSR build, atomic-free: MSD bucket sort (group by dst>>8, then by dst&255).
// ---------------------------------------------------------------------------
__global__ __launch_bounds__(256)
void p1_hist(const int* __restrict__ dst, int* __restrict__ ghist,
             int E, int B1, int nbins1)
{
  __shared__ int hist[256];
  int tid = threadIdx.x, blk = blockIdx.x;
  hist[tid] = 0;
  __syncthreads();
  int base = blk * SORT_CHUNK;
  int end_ = min(E, base + SORT_CHUNK);
  for (int i = base + tid; i < end_; i += 256)
    atomicAdd(&hist[dst[i] >> 8], 1);          // LDS atomic
  __syncthreads();
  if (tid < nbins1) ghist[tid * B1 + blk] = hist[tid];
}

// chunk-local exclusive scan (verified) + chunk totals
__global__ __launch_bounds__(256)
void scan1(const int* __restrict__ count, int* __restrict__ excl,
           int* __restrict__ bsum, int n)
{
  __shared__ int s[256];
  int tid = threadIdx.x;
  int i = blockIdx.x * 256 + tid;
  int v = (i < n) ? count[i] : 0;
  s[tid] = v;
  __syncthreads();
  #pragma unroll
  for (int d = 1; d < 256; d <<= 1) {
    int t = (tid >= d) ? s[tid - d] : 0;
    __syncthreads();
    s[tid] += t;
    __syncthreads();
  }
  if (i < n) excl[i] = s[tid] - v;
  if (tid == 255) bsum[blockIdx.x] = s[255];
}

__global__ __launch_bounds__(256)
void scan2(int* __restrict__ bsum, int nb)
{
  __shared__ int s[256];
  int tid = threadIdx.x;
  int v = (tid < nb) ? bsum[tid] : 0;
  s[tid] = v;
  __syncthreads();
  #pragma unroll
  for (int d = 1; d < 256; d <<= 1) {
    int t = (tid >= d) ? s[tid - d] : 0;
    __syncthreads();
    s[tid] += t;
    __syncthreads();
  }
  if (tid < nb) bsum[tid] = s[tid] - v;
}

__global__ __launch_bounds__(256)
void scan_add(int* __restrict__ data, const int* __restrict__ bsum, int n)
{
  int i = blockIdx.x * 256 + threadIdx.x;
  if (i < n) data[i] += bsum[blockIdx.x];
}

__global__ __launch_bounds__(256)
void p1_scatter(const int* __restrict__ src, const int* __restrict__ dst,
                const int* __restrict__ goff, int2* __restrict__ tmp,
                int E, int B1, int nbins1)
{
  __shared__ int cur[256];
  int tid = threadIdx.x, blk = blockIdx.x;
  if (tid < nbins1) cur[tid] = goff[tid * B1 + blk];
  __syncthreads();
  int base = blk * SORT_CHUNK;
  int end_ = min(E, base + SORT_CHUNK);
  for (int i = base + tid; i < end_; i += 256) {
    int d = dst[i];
    int pos = atomicAdd(&cur[d >> 8], 1);      // LDS atomic
    tmp[pos] = make_int2(src[i], d);
  }
}

// One block per high-byte bucket: group by low byte; emits adj AND row_off.
__global__ __launch_bounds__(256)
void p2_sort(const int2* __restrict__ tmp, const int* __restrict__ goff,
             int* __restrict__ adj, int* __restrict__ row_off,
             int E, int B1, int nbins1, int N)
{
  __shared__ int hist[256], s[256], cur[256];
  int H = blockIdx.x, tid = threadIdx.x;
  int base = goff[H * B1];
  int end_ = (H + 1 < nbins1) ? goff[(H + 1) * B1] : E;

  hist[tid] = 0;
  __syncthreads();
  for (int i = base + tid; i < end_; i += 256)
    atomicAdd(&hist[tmp[i].y & 255], 1);       // LDS atomic
  __syncthreads();
  int v = hist[tid];
  s[tid] = v;
  __syncthreads();
  #pragma unroll
  for (int d = 1; d < 256; d <<= 1) {
    int t = (tid >= d) ? s[tid - d] : 0;
    __syncthreads();
    s[tid] += t;
    __syncthreads();
  }
  int excl = s[tid] - v;
  cur[tid] = base + excl;
  int node = H * 256 + tid;
  if (node < N)  row_off[node] = base + excl;
  if (node == N) row_off[N] = E;
  if (H == 0 && tid == 0 && (N & 255) == 0) row_off[N] = E;
  __syncthreads();
  for (int i = base + tid; i < end_; i += 256) {
    int2 p = tmp[i];
    int pos = atomicAdd(&cur[p.y & 255], 1);   // LDS atomic
    adj[pos] = p.x;
  }
}

// ---------------------------------------------------------------------------
// One-time converts
// ---------------------------------------------------------------------------
__global__ __launch_bounds__(256)
void w_to_bf16t(const float* __restrict__ W, unsigned short* __restrict__ out, int total)
{
  int idx = blockIdx.x * 256 + threadIdx.x;
  if (idx >= total) return;
  int m = idx >> 14, ck = idx & 16383, c = ck >> 7, k = ck & 127;
  out[idx] = f2b(W[m * 16384 + k * 128 + c]);
}

__global__ __launch_bounds__(256)
void x_to_bf16(const float* __restrict__ x, unsigned short* __restrict__ xb, long long n4)
{
  long long i = (long long)blockIdx.x * 256 + threadIdx.x;
  if (i >= n4) return;
  float4 v = ((const float4*)x)[i];
  ushort4 o;
  o.x = f2b(v.x); o.y = f2b(v.y); o.z = f2b(v.z); o.w = f2b(v.w);
  ((ushort4*)xb)[i] = o;
}

__global__ void init_ss(float* __restrict__ ss)
{
  ss[threadIdx.x] = (threadIdx.x < NF) ? 1.f : 0.f;   // identity affine for layer 0
}

// ---------------------------------------------------------------------------
// Gather + fused BN affine of the previous layer (identity for layer 0):
//   agg[i] = bf16( sc * (h[i] + sum_j h[j]) + (deg+1) * sh )
// One WAVE per node: 4 sub-groups of 16 lanes, neighbors strided by 4.
// Depth-4 software pipeline: 4 independent row loads in flight per sub.
// ---------------------------------------------------------------------------
__global__ __launch_bounds__(256)
void gather_bn(const unsigned short* __restrict__ h, const int* __restrict__ row_off,
               const int* __restrict__ adj, const float* __restrict__ ss,
               unsigned short* __restrict__ agg, int n)
{
  int wv  = threadIdx.x >> 6;
  int l   = threadIdx.x & 63;
  int sub = l >> 4, llo = l & 15;
  int node = blockIdx.x * 4 + wv;
  if (node >= n) return;
  int beg = row_off[node], end = row_off[node + 1];

  float acc[8] = {0.f, 0.f, 0.f, 0.f, 0.f, 0.f, 0.f, 0.f};
  if (sub == 0)
    addbf8(acc, *(const uint4*)(h + (size_t)node * NF + llo * 8));   // self term

  int e = beg + sub;
  for (; e + 12 < end; e += 16) {            // 4 edges for this sub
    int s0 = adj[e], s1 = adj[e + 4], s2 = adj[e + 8], s3 = adj[e + 12];
    uint4 v0 = *(const uint4*)(h + (size_t)s0 * NF + llo * 8);
    uint4 v1 = *(const uint4*)(h + (size_t)s1 * NF + llo * 8);
    uint4 v2 = *(const uint4*)(h + (size_t)s2 * NF + llo * 8);
    uint4 v3 = *(const uint4*)(h + (size_t)s3 * NF + llo * 8);
    addbf8(acc, v0); addbf8(acc, v1); addbf8(acc, v2); addbf8(acc, v3);
  }
  for (; e < end; e += 4)
    addbf8(acc, *(const uint4*)(h + (size_t)adj[e] * NF + llo * 8));

  #pragma unroll
  for (int j = 0; j < 8; ++j) {
    acc[j] += __shfl_xor(acc[j], 16, 64);
    acc[j] += __shfl_xor(acc[j], 32, 64);
  }

  if (sub == 0) {
    float dp1 = (float)(end - beg + 1);
    unsigned short r[8];
    #pragma unroll
    for (int j = 0; j < 8; ++j) {
      float sc = ss[llo * 8 + j];
      float sh = ss[NF + llo * 8 + j];
      r[j] = f2b(fmaf(acc[j], sc, dp1 * sh));
    }
    uint4 o;
    o.x = (unsigned)r[0] | ((unsigned)r[1] << 16);
    o.y = (unsigned)r[2] | ((unsigned)r[3] << 16);
    o.z = (unsigned)r[4] | ((unsigned)r[5] << 16);
    o.w = (unsigned)r[6] | ((unsigned)r[7] << 16);
    *(uint4*)(agg + (size_t)node * NF + llo * 8) = o;
  }
}

// ---------------------------------------------------------------------------
// Fused MLP via MFMA bf16 (verified round 7/8): v = relu(relu(agg@W1+b1)@W2+b2)
// + fp64 BN partials. B-fragments straight from global (L2-broadcast W^T).
// ---------------------------------------------------------------------------
template<bool LAST>
__global__ __launch_bounds__(256)
void gemm12(const unsigned short* __restrict__ agg,
            const unsigned short* __restrict__ w1t, const float* __restrict__ b1,
            const unsigned short* __restrict__ w2t, const float* __restrict__ b2,
            float* __restrict__ vout, unsigned short* __restrict__ vb16,
            double* __restrict__ part, int nrows, int nblk)
{
  __shared__ __align__(16) unsigned short Alds[BM * NF];   // 32 KB

  const int tid = threadIdx.x;
  const int wid = tid >> 6;
  const int l   = tid & 63;
  const int lhi = l >> 4;
  const int llo = l & 15;
  const int row0 = blockIdx.x * BM;

  #pragma unroll
  for (int i = 0; i < 8; ++i) {
    int fidx = tid + 256 * i;
    int r = fidx >> 4, c16 = fidx & 15;
    int grow = row0 + r;
    uint4 v = make_uint4(0u, 0u, 0u, 0u);
    if (grow < nrows) v = *(const uint4*)(agg + (size_t)grow * NF + c16 * 8);
    int off = r * 256 + ((c16 * 16) ^ ((r & 7) << 4));
    *(uint4*)((char*)Alds + off) = v;
  }

  float b1v[8], b2v[8];
  #pragma unroll
  for (int c = 0; c < 8; ++c) {
    b1v[c] = b1[c * 16 + llo];
    b2v[c] = b2[c * 16 + llo];
  }

  const short8* w1v = (const short8*)w1t;   // [128 rows][16 short8]
  const short8* w2v = (const short8*)w2t;

  f32x4 acc[2][8];
  #pragma unroll
  for (int s = 0; s < 2; ++s)
    #pragma unroll
    for (int c = 0; c < 8; ++c) acc[s][c] = (f32x4){0.f, 0.f, 0.f, 0.f};

  __syncthreads();

  #pragma unroll
  for (int t = 0; t < 4; ++t) {
    short8 af[2];
    #pragma unroll
    for (int s = 0; s < 2; ++s) {
      int r = wid * 32 + s * 16 + llo;
      int off = r * 256 + ((t * 64 + lhi * 16) ^ ((r & 7) << 4));
      af[s] = *(const short8*)((const char*)Alds + off);
    }
    #pragma unroll
    for (int c = 0; c < 8; ++c) {
      short8 bf = w1v[(c * 16 + llo) * 16 + t * 4 + lhi];
      acc[0][c] = __builtin_amdgcn_mfma_f32_16x16x32_bf16(af[0], bf, acc[0][c], 0, 0, 0);
      acc[1][c] = __builtin_amdgcn_mfma_f32_16x16x32_bf16(af[1], bf, acc[1][c], 0, 0, 0);
    }
  }

  __syncthreads();

  #pragma unroll
  for (int s = 0; s < 2; ++s)
    #pragma unroll
    for (int c = 0; c < 8; ++c) {
      int colg = c * 16 + llo;
      #pragma unroll
      for (int q = 0; q < 4; ++q) {
        int r = wid * 32 + s * 16 + lhi * 4 + q;
        float u = fmaxf(acc[s][c][q] + b1v[c], 0.f);
        int off = r * 256 + ((colg * 2) ^ ((r & 7) << 4));
        *(unsigned short*)((char*)Alds + off) = f2b(u);
      }
    }
  #pragma unroll
  for (int s = 0; s < 2; ++s)
    #pragma unroll
    for (int c = 0; c < 8; ++c) acc[s][c] = (f32x4){0.f, 0.f, 0.f, 0.f};

  __syncthreads();

  #pragma unroll
  for (int t = 0; t < 4; ++t) {
    short8 af[2];
    #pragma unroll
    for (int s = 0; s < 2; ++s) {
      int r = wid * 32 + s * 16 + llo;
      int off = r * 256 + ((t * 64 + lhi * 16) ^ ((r & 7) << 4));
      af[s] = *(const short8*)((const char*)Alds + off);
    }
    #pragma unroll
    for (int c = 0; c < 8; ++c) {
      short8 bf = w2v[(c * 16 + llo) * 16 + t * 4 + lhi];
      acc[0][c] = __builtin_amdgcn_mfma_f32_16x16x32_bf16(af[0], bf, acc[0][c], 0, 0, 0);
      acc[1][c] = __builtin_amdgcn_mfma_f32_16x16x32_bf16(af[1], bf, acc[1][c], 0, 0, 0);
    }
  }

  float ts[8] = {0.f, 0.f, 0.f, 0.f, 0.f, 0.f, 0.f, 0.f};
  float tq[8] = {0.f, 0.f, 0.f, 0.f, 0.f, 0.f, 0.f, 0.f};
  #pragma unroll
  for (int s = 0; s < 2; ++s)
    #pragma unroll
    for (int c = 0; c < 8; ++c) {
      int colg = c * 16 + llo;
      #pragma unroll
      for (int q = 0; q < 4; ++q) {
        int rloc = wid * 32 + s * 16 + lhi * 4 + q;
        int row = row0 + rloc;
        if (row < nrows) {
          float vv = fmaxf(acc[s][c][q] + b2v[c], 0.f);
          ts[c] += vv; tq[c] += vv * vv;
          if (LAST) vout[(size_t)row * NF + colg] = vv;
          else      vb16[(size_t)row * NF + colg] = f2b(vv);
        }
      }
    }

  __syncthreads();
  double* redS = (double*)Alds;    // [16][128]
  double* redQ = redS + 16 * NF;   // [16][128]
  int prow = wid * 4 + lhi;
  #pragma unroll
  for (int c = 0; c < 8; ++c) {
    redS[prow * NF + c * 16 + llo] = (double)ts[c];
    redQ[prow * NF + c * 16 + llo] = (double)tq[c];
  }
  __syncthreads();
  if (tid < NF) {
    double s = 0.0;
    #pragma unroll
    for (int r = 0; r < 16; ++r) s += redS[r * NF + tid];
    part[(size_t)blockIdx.x * NF + tid] = s;
  } else {
    int c = tid - NF;
    double s = 0.0;
    #pragma unroll
    for (int r = 0; r < 16; ++r) s += redQ[r * NF + c];
    part[(size_t)nblk * NF + (size_t)blockIdx.x * NF + c] = s;
  }
}

// ---------------------------------------------------------------------------
// BN finalize (verified round 8): 8 blocks x 1024 thr, fixed-order fp64 tree.
// ---------------------------------------------------------------------------
__global__ __launch_bounds__(1024)
void bn_stats_final(const double* __restrict__ part,
                    const float* __restrict__ gamma,
                    const float* __restrict__ beta,
                    float* __restrict__ ss, int nrows, int nblk)
{
  __shared__ double redS[64][17], redQ[64][17];
  int cl  = threadIdx.x & 15;
  int seg = threadIdx.x >> 4;
  int c = blockIdx.x * 16 + cl;
  double s = 0.0, s2 = 0.0;
  for (int b = seg; b < nblk; b += 64) {
    s  += part[(size_t)b * NF + c];
    s2 += part[(size_t)nblk * NF + (size_t)b * NF + c];
  }
  redS[seg][cl] = s;
  redQ[seg][cl] = s2;
  __syncthreads();
  #pragma unroll
  for (int d = 32; d >= 1; d >>= 1) {
    if (seg < d) {
      redS[seg][cl] += redS[seg + d][cl];
      redQ[seg][cl] += redQ[seg + d][cl];
    }
    __syncthreads();
  }
  if (seg == 0) {
    double invN = 1.0 / (double)nrows;
    double mu  = redS[0][cl] * invN;
    double var = redQ[0][cl] * invN - mu * mu;
    double sc  = (double)gamma[c] / sqrt(var + (double)BN_EPS_C);
    ss[c]      = (float)sc;
    ss[NF + c] = (float)((double)beta[c] - mu * sc);
  }
}

// ---------------------------------------------------------------------------
__global__ __launch_bounds__(256)
void bn_apply(const float* __restrict__ v, const float* __restrict__ ss,
              float* __restrict__ out, int nrows)
{
  long long i = (long long)blockIdx.x * 256 + threadIdx.x;
  long long total = (long long)nrows * (NF / 4);
  if (i >= total) return;
  int c = (int)(i & 31) * 4;
  float4 val = ((const float4*)v)[i];
  float4 o;
  o.x = fmaf(val.x, ss[c + 0], ss[NF + c + 0]);
  o.y = fmaf(val.y, ss[c + 1], ss[NF + c + 1]);
  o.z = fmaf(val.z, ss[c + 2], ss[NF + c + 2]);
  o.w = fmaf(val.w, ss[c + 3], ss[NF + c + 3]);
  ((float4*)out)[i] = o;
}

__global__ void copy_batch(const int* __restrict__ b, float* __restrict__ o, int n)
{
  int i = blockIdx.x * 256 + threadIdx.x;
  if (i < n) o[i] = (float)b[i];
}

// ---------------------------------------------------------------------------
extern "C" void kernel_launch(void* const* d_in, const int* in_sizes, int n_in,
                              void* d_out, int out_size, void* d_ws, size_t ws_size,
                              hipStream_t stream)
{
  const float* x     = (const float*)d_in[0];
  const int*   ei    = (const int*)  d_in[1];
  const int*   batch = (const int*)  d_in[2];
  const float* W1    = (const float*)d_in[3];
  const float* b1    = (const float*)d_in[4];
  const float* W2    = (const float*)d_in[5];
  const float* b2    = (const float*)d_in[6];
  const float* gamma = (const float*)d_in[7];
  const float* beta  = (const float*)d_in[8];

  const int N = in_sizes[2];
  const int E = in_sizes[1] / 2;
  const int L = in_sizes[4] / NF;

  const int* src = ei;
  const int* dst = ei + E;

  const int nblk   = (N + BM - 1) / BM;
  const int B1     = (E + SORT_CHUNK - 1) / SORT_CHUNK;   // p1 blocks
  const int nbins1 = (N + 255) >> 8;                      // high-byte buckets
  const int nscan  = nbins1 * B1;
  const int scanBlocks = (nscan + 255) / 256;

  // workspace layout
  double* part = (double*)d_ws;                                 // 2*nblk*128
  float*  ss   = (float*)(part + 2 * (size_t)nblk * NF);        // 256
  unsigned short* aggb = (unsigned short*)(ss + 256);           // N*128 bf16
  unsigned short* vb   = aggb + (size_t)N * NF;                 // N*128 bf16
  unsigned short* wt   = vb + (size_t)N * NF;                   // 6*16384 bf16
  int* row_off = (int*)(wt + 6 * 16384);                        // N+1
  int* adj     = row_off + (N + 1);                             // E
  // CSR-build temporaries overlap layer buffers (build finishes before use):
  int2* tmp   = (int2*)aggb;                                    // E int2 (< N*128*2B)
  int*  ghist = (int*)vb;                                       // nscan
  int*  goff  = ghist + nscan;                                  // nscan
  int*  bsum  = goff + nscan;                                   // scanBlocks

  float* vbuf = (float*)d_out;                                  // N*128 fp32 (final)
  float* outBatch = vbuf + (size_t)N * NF;
  unsigned short* xb = (unsigned short*)vbuf;                   // N*128 bf16 (temp)

  const int nBlocks256 = (N + 255) / 256;
  const int bnBlocks   = (int)(((long long)N * (NF / 4) + 255) / 256);
  const long long x4   = (long long)N * NF / 4;

  // ---- one-time prep ----
  x_to_bf16<<<(int)((x4 + 255) / 256), 256, 0, stream>>>(x, xb, x4);
  init_ss<<<1, 256, 0, stream>>>(ss);
  w_to_bf16t<<<(3 * 16384 + 255) / 256, 256, 0, stream>>>(W1, wt, 3 * 16384);
  w_to_bf16t<<<(3 * 16384 + 255) / 256, 256, 0, stream>>>(W2, wt + 3 * 16384, 3 * 16384);

  // ---- CSR build, atomic-free ----
  p1_hist<<<B1, 256, 0, stream>>>(dst, ghist, E, B1, nbins1);
  scan1<<<scanBlocks, 256, 0, stream>>>(ghist, goff, bsum, nscan);
  scan2<<<1, 256, 0, stream>>>(bsum, scanBlocks);
  scan_add<<<scanBlocks, 256, 0, stream>>>(goff, bsum, nscan);
  p1_scatter<<<B1, 256, 0, stream>>>(src, dst, goff, tmp, E, B1, nbins1);
  p2_sort<<<nbins1, 256, 0, stream>>>(tmp, goff, adj, row_off, E, B1, nbins1, N);

  // ---- layers ----
  for (int ly = 0; ly < L; ++ly) {
    const unsigned short* hsrc = (ly == 0) ? xb : vb;
    gather_bn<<<(N + 3) / 4, 256, 0, stream>>>(hsrc, row_off, adj, ss, aggb, N);

    const unsigned short* w1t = wt + (size_t)ly * 16384;
    const unsigned short* w2t = wt + (size_t)(3 + ly) * 16384;
    if (ly == L - 1)
      gemm12<true><<<nblk, 256, 0, stream>>>(aggb, w1t, b1 + ly * NF, w2t, b2 + ly * NF,
                                             vbuf, vb, part, N, nblk);
    else
      gemm12<false><<<nblk, 256, 0, stream>>>(aggb, w1t, b1 + ly * NF, w2t, b2 + ly * NF,
                                              vbuf, vb, part, N, nblk);
    bn_stats_final<<<8, 1024, 0, stream>>>(part, gamma + ly * NF, beta + ly * NF,
                                           ss, N, nblk);
  }

  // final: h = BN(v) in place, then batch
  bn_apply<<<bnBlocks, 256, 0, stream>>>(vbuf, ss, vbuf, N);
  copy_batch<<<nBlocks256, 256, 0, stream>>>(batch, outBatch, N);
}